// Round 5
// baseline (3068.285 us; speedup 1.0000x reference)
//
#include <hip/hip_runtime.h>
#include <math.h>

// TransitionNER head:  hidden = tanh(concat(4x[B,1024]) @ W1 + b1)
//                      logits = hidden @ W2 + b2 ; masked log-softmax ; argmax + gold gather
// B=16384, H=1024, A=20, K=4096.
//
// Round 5: refine_kernel restructured for latency:
//  - 1024-thread block (4 waves/SIMD TLP; was 1 wave/SIMD -> zero latency cover)
//  - thread owns 1 column x 4 rows (coalesced W1 dword loads)
//  - depth-2 software pipeline: two 16-entry reg buffers (wa/wb), refill of one
//    in flight under the other's 512 SIMD-cycle compute window
//  - tanh + 20-way head fused into the same block (waves 0..3), reusing LDS
// gemm/xpack/wpack/head/detect unchanged.

#define BTOT 16384
#define HD   1024
#define NACT 20
#define KTOT 4096
#define KT_N 128          // number of 32-wide k tiles

typedef __attribute__((ext_vector_type(8))) short short8;
typedef __attribute__((ext_vector_type(4))) float f32x4;

#define MFMA(a, b, c) __builtin_amdgcn_mfma_f32_16x16x32_bf16((a), (b), (c), 0, 0, 0)

// ---------------- global -> LDS direct load (16B) ----------------
__device__ __forceinline__ void gload16(const void* g, void* l)
{
    auto gp = (const __attribute__((address_space(1))) unsigned int*)((uintptr_t)g);
    auto lp = (__attribute__((address_space(3))) unsigned int*)((uintptr_t)l);
    __builtin_amdgcn_global_load_lds(gp, lp, 16, 0, 0);
}

// ---------------- bf16 split helpers (RNE) ----------------
__device__ __forceinline__ void split8(const float4 v0, const float4 v1,
                                       int4& hi, int4& lo)
{
    const float f[8] = {v0.x, v0.y, v0.z, v0.w, v1.x, v1.y, v1.z, v1.w};
    unsigned hp[4], lp[4];
#pragma unroll
    for (int i = 0; i < 4; ++i) {
        const unsigned u0 = __float_as_uint(f[2 * i]);
        const unsigned u1 = __float_as_uint(f[2 * i + 1]);
        const unsigned r0 = u0 + 0x7FFFu + ((u0 >> 16) & 1u);
        const unsigned r1 = u1 + 0x7FFFu + ((u1 >> 16) & 1u);
        hp[i] = (r0 >> 16) | (r1 & 0xFFFF0000u);
        const float h0 = __uint_as_float(r0 & 0xFFFF0000u);
        const float h1 = __uint_as_float(r1 & 0xFFFF0000u);
        const float d0 = f[2 * i] - h0;
        const float d1 = f[2 * i + 1] - h1;
        const unsigned s0 = __float_as_uint(d0);
        const unsigned s1 = __float_as_uint(d1);
        const unsigned q0 = s0 + 0x7FFFu + ((s0 >> 16) & 1u);
        const unsigned q1 = s1 + 0x7FFFu + ((s1 >> 16) & 1u);
        lp[i] = (q0 >> 16) | (q1 & 0xFFFF0000u);
    }
    hi = make_int4((int)hp[0], (int)hp[1], (int)hp[2], (int)hp[3]);
    lo = make_int4((int)lp[0], (int)lp[1], (int)lp[2], (int)lp[3]);
}

// ---------------- mask dtype detection ----------------
__global__ __launch_bounds__(256) void detect_mask_kernel(
    const unsigned int* __restrict__ w, int nwords, int* __restrict__ ctr)
{
    int c0 = 0, c1 = 0, c2 = 0, c3 = 0;
    for (int i = blockIdx.x * 256 + threadIdx.x; i < nwords; i += gridDim.x * 256) {
        unsigned int v = w[i];
        c0 += (v & 0x000000FFu) ? 1 : 0;
        c1 += (v & 0x0000FF00u) ? 1 : 0;
        c2 += (v & 0x00FF0000u) ? 1 : 0;
        c3 += (v & 0xFF000000u) ? 1 : 0;
    }
#pragma unroll
    for (int off = 32; off; off >>= 1) {
        c0 += __shfl_xor(c0, off, 64);
        c1 += __shfl_xor(c1, off, 64);
        c2 += __shfl_xor(c2, off, 64);
        c3 += __shfl_xor(c3, off, 64);
    }
    if ((threadIdx.x & 63) == 0) {
        atomicAdd(&ctr[0], c0);
        atomicAdd(&ctr[1], c1);
        atomicAdd(&ctr[2], c2);
        atomicAdd(&ctr[3], c3);
    }
}

// ---------------- X pack: f32 rows -> swizzled bf16 hi/lo tile images ----------------
__global__ __launch_bounds__(256) void xpack_kernel(
    const float* __restrict__ A0, const float* __restrict__ A1,
    const float* __restrict__ A2, const float* __restrict__ A3,
    char* __restrict__ Xp, int rowBase)
{
    const int b  = blockIdx.x;
    const int t  = threadIdx.x;
    const int mt = b >> 6;
    const int kt = ((b & 63) << 1) + (t >> 7);
    const int rr = t & 127;

    const int seg = kt >> 5;
    const float* __restrict__ s =
        (seg == 0) ? A0 : (seg == 1) ? A1 : (seg == 2) ? A2 : A3;
    const float4* sp = (const float4*)(s + (size_t)(rowBase + mt * 128 + rr) * HD
                                         + (kt & 31) * 32);

    int4 hi[4], lo[4];
#pragma unroll
    for (int c = 0; c < 4; ++c)
        split8(sp[2 * c], sp[2 * c + 1], hi[c], lo[c]);

    char* rowp = Xp + (((size_t)(mt * KT_N + kt)) << 14) + rr * 128;
    const int r7 = rr & 7;
#pragma unroll
    for (int c = 0; c < 4; ++c) {
        const int ph = (c ^ r7) << 4;
        *(int4*)(rowp + ph)        = hi[c];
        *(int4*)(rowp + (ph ^ 64)) = lo[c];
    }
}

// ---------------- W pack: [K][N] f32 -> swizzled bf16 hi/lo tile images ----------------
__global__ __launch_bounds__(256) void wpack_kernel(
    const float* __restrict__ W1, char* __restrict__ Wp)
{
    const int b  = blockIdx.x;
    const int t  = threadIdx.x;
    const int nt = b >> 7;
    const int kt = b & 127;
    const int nn = t & 127;
    const int h  = t >> 7;

    float f[16];
#pragma unroll
    for (int kk = 0; kk < 16; ++kk)
        f[kk] = W1[(size_t)(kt * 32 + h * 16 + kk) * HD + nt * 128 + nn];

    int4 hi0, lo0, hi1, lo1;
    split8(make_float4(f[0], f[1], f[2], f[3]),
           make_float4(f[4], f[5], f[6], f[7]), hi0, lo0);
    split8(make_float4(f[8], f[9], f[10], f[11]),
           make_float4(f[12], f[13], f[14], f[15]), hi1, lo1);

    char* rowp = Wp + (((size_t)(nt * KT_N + kt)) << 14) + nn * 128;
    const int r7 = nn & 7;
    const int s0 = ((2 * h) ^ r7) << 4;
    const int s1 = ((2 * h + 1) ^ r7) << 4;
    *(int4*)(rowp + s0)        = hi0;
    *(int4*)(rowp + s1)        = hi1;
    *(int4*)(rowp + (s0 ^ 64)) = lo0;
    *(int4*)(rowp + (s1 ^ 64)) = lo1;
}

// ---------------- GEMM1 (pure MFMA, 3-pass) + bias + tanh ----------------
__global__ __launch_bounds__(256, 2) void gemm1_mfma_kernel(
    const char* __restrict__ Xp, const char* __restrict__ Wp,
    const float* __restrict__ b1, float* __restrict__ hidden)
{
    __shared__ __align__(16) char smem[65536];   // 2 buf x (A 16KB + B 16KB)

    const int nwg = gridDim.x;
    const int q = nwg >> 3;
    const int newbid = (blockIdx.x & 7) * q + (blockIdx.x >> 3);
    const int mt = newbid >> 3;
    const int nt = newbid & 7;

    const int t    = threadIdx.x;
    const int lane = t & 63;
    const int wid  = t >> 6;
    const int wr = wid >> 1, wc = wid & 1;
    const int lrow = lane & 15;
    const int lk   = lane >> 4;

    const char* gA = Xp + (((size_t)mt * KT_N) << 14);
    const char* gB = Wp + (((size_t)nt * KT_N) << 14);

    const int so0 = t << 4;

    const unsigned aOff = (unsigned)(wr * 64 + lrow) * 128 + (((unsigned)lk ^ (unsigned)(lrow & 7)) << 4);
    const unsigned bOff = (unsigned)(wc * 64 + lrow) * 128 + (((unsigned)lk ^ (unsigned)(lrow & 7)) << 4);

    f32x4 acc[4][4];
#pragma unroll
    for (int i = 0; i < 4; ++i)
#pragma unroll
        for (int j = 0; j < 4; ++j) acc[i][j] = (f32x4){0.f, 0.f, 0.f, 0.f};

    // prologue: stage kt=0 into buf 0
#pragma unroll
    for (int i = 0; i < 4; ++i) {
        gload16(gA + so0 + i * 4096, smem + so0 + i * 4096);
        gload16(gB + so0 + i * 4096, smem + 16384 + so0 + i * 4096);
    }
    __syncthreads();

    int cur = 0;
    for (int kt = 0; kt < KT_N; ++kt) {
        if (kt + 1 < KT_N) {
            const char* nA = gA + (((size_t)(kt + 1)) << 14);
            const char* nB = gB + (((size_t)(kt + 1)) << 14);
            char* lA = smem + (cur ^ 1) * 32768;
            char* lB = lA + 16384;
#pragma unroll
            for (int i = 0; i < 4; ++i) {
                gload16(nA + so0 + i * 4096, lA + so0 + i * 4096);
                gload16(nB + so0 + i * 4096, lB + so0 + i * 4096);
            }
        }

        const char* lA = smem + cur * 32768;
        const char* lB = lA + 16384;

        short8 ah[4], al[4], bh[4], bl[4];
#pragma unroll
        for (int f = 0; f < 4; ++f) {
            ah[f] = *(const short8*)(lA + (aOff + f * 2048));
            al[f] = *(const short8*)(lA + ((aOff + f * 2048) ^ 64));
            bh[f] = *(const short8*)(lB + (bOff + f * 2048));
            bl[f] = *(const short8*)(lB + ((bOff + f * 2048) ^ 64));
        }
#pragma unroll
        for (int fi = 0; fi < 4; ++fi)
#pragma unroll
            for (int fj = 0; fj < 4; ++fj)
                acc[fi][fj] = MFMA(ah[fi], bh[fj], acc[fi][fj]);
#pragma unroll
        for (int fi = 0; fi < 4; ++fi)
#pragma unroll
            for (int fj = 0; fj < 4; ++fj)
                acc[fi][fj] = MFMA(ah[fi], bl[fj], acc[fi][fj]);
#pragma unroll
        for (int fi = 0; fi < 4; ++fi)
#pragma unroll
            for (int fj = 0; fj < 4; ++fj)
                acc[fi][fj] = MFMA(al[fi], bh[fj], acc[fi][fj]);

        __syncthreads();
        cur ^= 1;
    }

    // epilogue: bias + tanh
#pragma unroll
    for (int fj = 0; fj < 4; ++fj) {
        const int col = nt * 128 + wc * 64 + fj * 16 + lrow;
        const float bias = b1[col];
#pragma unroll
        for (int fi = 0; fi < 4; ++fi) {
            const int row0 = mt * 128 + wr * 64 + fi * 16 + lk * 4;
#pragma unroll
            for (int r = 0; r < 4; ++r)
                hidden[(size_t)(row0 + r) * HD + col] = tanhf(acc[fi][fj][r] + bias);
        }
    }
}

// ---------------- shared head/refine epilogue ----------------
__device__ __forceinline__ void finish_row(
    const float* __restrict__ acc, const float* __restrict__ b2,
    const void* __restrict__ mask, const int* __restrict__ real_actions,
    int fmt, int row, float* __restrict__ out,
    int* __restrict__ flagCnt, int* __restrict__ flagList, int lane)
{
    float masked[NACT];
#pragma unroll
    for (int a = 0; a < NACT; ++a) {
        const float lg = acc[a] + b2[a];
        bool valid;
        if (fmt == 0)      valid = ((const unsigned char*)mask)[(size_t)row * NACT + a] != 0;
        else if (fmt == 1) valid = ((const int*)mask)[(size_t)row * NACT + a] != 0;
        else               valid = ((const float*)mask)[(size_t)row * NACT + a] != 0.f;
        masked[a] = valid ? lg : -1e9f;
    }
    float m = masked[0], m2 = -3e38f;
    int amax = 0;
#pragma unroll
    for (int a = 1; a < NACT; ++a) {
        const float v = masked[a];
        if (v > m) { m2 = m; m = v; amax = a; }
        else if (v > m2) m2 = v;
    }
    float s = 0.f;
#pragma unroll
    for (int a = 0; a < NACT; ++a) s += expf(masked[a] - m);
    const float lse = m + logf(s);
    const int ga = real_actions[row];
    float gl = masked[0];
#pragma unroll
    for (int a = 1; a < NACT; ++a) gl = (ga == a) ? masked[a] : gl;
    if (lane == 0) {
        out[row] = (float)amax;
        out[BTOT + row] = gl - lse;
        if (flagList != nullptr && (m - m2) < 1e-3f) {
            const int ix = atomicAdd(flagCnt, 1);
            flagList[ix] = row;
        }
    }
}

// ---------------- head: logits, masked log-softmax, argmax, loss, gap-flag ----------------
__global__ __launch_bounds__(256) void head_kernel(
    const float* __restrict__ hidden, const float* __restrict__ W2,
    const float* __restrict__ b2, const void* __restrict__ mask,
    const int* __restrict__ real_actions, int* __restrict__ ctr,
    int* __restrict__ flagList, float* __restrict__ out, int rowBase)
{
    const int lane     = threadIdx.x & 63;
    const int localRow = blockIdx.x * 4 + (threadIdx.x >> 6);
    const int row      = rowBase + localRow;

    float acc[NACT];
#pragma unroll
    for (int a = 0; a < NACT; ++a) acc[a] = 0.f;

    const float* hrow = hidden + (size_t)localRow * HD;
#pragma unroll 4
    for (int j = 0; j < 16; ++j) {
        const int h = lane + 64 * j;
        const float hv = hrow[h];
        const float4* w4 = (const float4*)(W2 + (size_t)h * NACT);
        const float4 w0 = w4[0], w1 = w4[1], w2 = w4[2], w3 = w4[3], w4v = w4[4];
        acc[0]  = fmaf(hv, w0.x,  acc[0]);  acc[1]  = fmaf(hv, w0.y,  acc[1]);
        acc[2]  = fmaf(hv, w0.z,  acc[2]);  acc[3]  = fmaf(hv, w0.w,  acc[3]);
        acc[4]  = fmaf(hv, w1.x,  acc[4]);  acc[5]  = fmaf(hv, w1.y,  acc[5]);
        acc[6]  = fmaf(hv, w1.z,  acc[6]);  acc[7]  = fmaf(hv, w1.w,  acc[7]);
        acc[8]  = fmaf(hv, w2.x,  acc[8]);  acc[9]  = fmaf(hv, w2.y,  acc[9]);
        acc[10] = fmaf(hv, w2.z,  acc[10]); acc[11] = fmaf(hv, w2.w,  acc[11]);
        acc[12] = fmaf(hv, w3.x,  acc[12]); acc[13] = fmaf(hv, w3.y,  acc[13]);
        acc[14] = fmaf(hv, w3.z,  acc[14]); acc[15] = fmaf(hv, w3.w,  acc[15]);
        acc[16] = fmaf(hv, w4v.x, acc[16]); acc[17] = fmaf(hv, w4v.y, acc[17]);
        acc[18] = fmaf(hv, w4v.z, acc[18]); acc[19] = fmaf(hv, w4v.w, acc[19]);
    }
#pragma unroll
    for (int off = 32; off; off >>= 1) {
#pragma unroll
        for (int a = 0; a < NACT; ++a) acc[a] += __shfl_xor(acc[a], off, 64);
    }

    const int c1 = ctr[1], c2 = ctr[2], c3 = ctr[3];
    const int fmt = (c1 > 0) ? 0 : ((c2 > 0 || c3 > 0) ? 2 : 1);

    finish_row(acc, b2, mask, real_actions, fmt, row, out, &ctr[4], flagList, lane);
}

// ---------------- exact-f32 refinement of flagged rows ----------------
// 1024 threads/block (4 waves/SIMD TLP), 4 rows/block, thread owns 1 column.
// Depth-2 pipelined W1 column loads (two 16-entry reg buffers).
__global__ __launch_bounds__(1024) void refine_kernel(
    const float* __restrict__ A0, const float* __restrict__ A1,
    const float* __restrict__ A2, const float* __restrict__ A3,
    const float* __restrict__ W1, const float* __restrict__ b1,
    const float* __restrict__ W2, const float* __restrict__ b2,
    const void* __restrict__ mask, const int* __restrict__ real_actions,
    const int* __restrict__ ctr, const int* __restrict__ list,
    float* __restrict__ out)
{
    __shared__ float xs[4][KTOT];   // 64 KiB; rows reused for hidden after k-loop
    const int tid = threadIdx.x;    // 0..1023 == owned column
    const int count = ctr[4];
    const int c1 = ctr[1], c2 = ctr[2], c3 = ctr[3];
    const int fmt = (c1 > 0) ? 0 : ((c2 > 0 || c3 > 0) ? 2 : 1);

    for (int base = blockIdx.x * 4; base < count; base += gridDim.x * 4) {
        const int nr = min(count - base, 4);
        for (int j = 0; j < nr; ++j) {
            const int row = list[base + j];
            for (int i = tid; i < KTOT; i += 1024) {
                const float* seg = (i < 1024) ? A0 : (i < 2048) ? A1 : (i < 3072) ? A2 : A3;
                xs[j][i] = seg[(size_t)row * HD + (i & 1023)];
            }
        }
        __syncthreads();

        float acc0 = 0.f, acc1 = 0.f, acc2 = 0.f, acc3 = 0.f;

        // depth-2 pipeline: wa = k0..k0+15, wb = k0+16..k0+31
        float wa[16], wb[16];
#pragma unroll
        for (int u = 0; u < 16; ++u) wa[u] = W1[(size_t)u * HD + tid];
#pragma unroll
        for (int u = 0; u < 16; ++u) wb[u] = W1[(size_t)(16 + u) * HD + tid];

        for (int k0 = 0; k0 < KTOT; k0 += 32) {
#pragma unroll
            for (int u = 0; u < 16; ++u) {
                const float w = wa[u];
                acc0 = fmaf(xs[0][k0 + u], w, acc0);
                acc1 = fmaf(xs[1][k0 + u], w, acc1);
                acc2 = fmaf(xs[2][k0 + u], w, acc2);
                acc3 = fmaf(xs[3][k0 + u], w, acc3);
            }
            if (k0 + 32 < KTOT) {
#pragma unroll
                for (int u = 0; u < 16; ++u)
                    wa[u] = W1[(size_t)(k0 + 32 + u) * HD + tid];
            }
#pragma unroll
            for (int u = 0; u < 16; ++u) {
                const float w = wb[u];
                acc0 = fmaf(xs[0][k0 + 16 + u], w, acc0);
                acc1 = fmaf(xs[1][k0 + 16 + u], w, acc1);
                acc2 = fmaf(xs[2][k0 + 16 + u], w, acc2);
                acc3 = fmaf(xs[3][k0 + 16 + u], w, acc3);
            }
            if (k0 + 48 < KTOT) {
#pragma unroll
                for (int u = 0; u < 16; ++u)
                    wb[u] = W1[(size_t)(k0 + 48 + u) * HD + tid];
            }
        }
        __syncthreads();

        // hidden rows back into xs[j][0..1023]
        const float bias = b1[tid];
        xs[0][tid] = tanhf(acc0 + bias);
        xs[1][tid] = tanhf(acc1 + bias);
        xs[2][tid] = tanhf(acc2 + bias);
        xs[3][tid] = tanhf(acc3 + bias);
        __syncthreads();

        // waves 0..3: one row each, 20-way head
        const int j = tid >> 6, lane = tid & 63;
        if (j < nr) {
            const int row = list[base + j];
            float a20[NACT];
#pragma unroll
            for (int a = 0; a < NACT; ++a) a20[a] = 0.f;
#pragma unroll 4
            for (int m = 0; m < 16; ++m) {
                const int h = lane + 64 * m;
                const float hv = xs[j][h];
                const float4* w4 = (const float4*)(W2 + (size_t)h * NACT);
                const float4 w0 = w4[0], w1 = w4[1], w2 = w4[2], w3 = w4[3], w4v = w4[4];
                a20[0]  = fmaf(hv, w0.x,  a20[0]);  a20[1]  = fmaf(hv, w0.y,  a20[1]);
                a20[2]  = fmaf(hv, w0.z,  a20[2]);  a20[3]  = fmaf(hv, w0.w,  a20[3]);
                a20[4]  = fmaf(hv, w1.x,  a20[4]);  a20[5]  = fmaf(hv, w1.y,  a20[5]);
                a20[6]  = fmaf(hv, w1.z,  a20[6]);  a20[7]  = fmaf(hv, w1.w,  a20[7]);
                a20[8]  = fmaf(hv, w2.x,  a20[8]);  a20[9]  = fmaf(hv, w2.y,  a20[9]);
                a20[10] = fmaf(hv, w2.z,  a20[10]); a20[11] = fmaf(hv, w2.w,  a20[11]);
                a20[12] = fmaf(hv, w3.x,  a20[12]); a20[13] = fmaf(hv, w3.y,  a20[13]);
                a20[14] = fmaf(hv, w3.z,  a20[14]); a20[15] = fmaf(hv, w3.w,  a20[15]);
                a20[16] = fmaf(hv, w4v.x, a20[16]); a20[17] = fmaf(hv, w4v.y, a20[17]);
                a20[18] = fmaf(hv, w4v.z, a20[18]); a20[19] = fmaf(hv, w4v.w, a20[19]);
            }
#pragma unroll
            for (int off = 32; off; off >>= 1) {
#pragma unroll
                for (int a = 0; a < NACT; ++a) a20[a] += __shfl_xor(a20[a], off, 64);
            }
            finish_row(a20, b2, mask, real_actions, fmt, row, out, nullptr, nullptr, lane);
        }
        __syncthreads();
    }
}

// ---------------- launcher ----------------
extern "C" void kernel_launch(void* const* d_in, const int* in_sizes, int n_in,
                              void* d_out, int out_size, void* d_ws, size_t ws_size,
                              hipStream_t stream)
{
    const float* buf_h = (const float*)d_in[0];
    const float* stk_h = (const float*)d_in[1];
    const float* out_h = (const float*)d_in[2];
    const float* act_h = (const float*)d_in[3];
    const float* W1    = (const float*)d_in[4];
    const float* b1    = (const float*)d_in[5];
    const float* W2    = (const float*)d_in[6];
    const float* b2    = (const float*)d_in[7];
    const void*  mask  = d_in[8];
    const int*   ra    = (const int*)d_in[9];
    float*       out   = (float*)d_out;

    // ws layout:
    //   [0,256)          : ctr (mask byte counters 0..3, flag count at [4])
    //   [256, 256+64K)   : flagged-row list (int[16384])
    //   then 16MB        : Wp tile images (8 nt x 128 kt x 16KB)
    //   then             : Xp chunk tile images (16KB per row)
    //   then             : hidden chunk buffer (4KB per row)
    int*  ctr      = (int*)d_ws;
    int*  flagList = (int*)((char*)d_ws + 256);
    char* Wp       = (char*)d_ws + 256 + 65536;
    const size_t wpBytes = (size_t)8 * KT_N * 16384;           // 16 MiB
    char* XpBase   = Wp + wpBytes;
    const size_t fixed = 256 + 65536 + wpBytes;

    hipMemsetAsync(d_ws, 0, 256, stream);
    detect_mask_kernel<<<64, 256, 0, stream>>>(
        (const unsigned int*)mask, BTOT * NACT / 4, ctr);
    wpack_kernel<<<8 * KT_N, 256, 0, stream>>>(W1, Wp);

    // chunk rows so Xp (16KB/row) + hidden (4KB/row) fit in the workspace
    const size_t perRow = 16384 + 4096;
    const size_t avail  = (ws_size > fixed) ? (ws_size - fixed) : 0;
    long maxRows = (long)(avail / perRow);
    int Bc;
    if (maxRows >= BTOT) Bc = BTOT;
    else {
        Bc = (int)((maxRows / 128) * 128);
        if (Bc <= 0) Bc = 128;
    }
    float* hidden = (float*)(XpBase + (size_t)Bc * 16384);

    for (int r0 = 0; r0 < BTOT; r0 += Bc) {
        const int rows = (BTOT - r0 < Bc) ? (BTOT - r0) : Bc;   // multiple of 128
        const int mtiles = rows / 128;
        xpack_kernel<<<mtiles * 64, 256, 0, stream>>>(
            buf_h, stk_h, out_h, act_h, XpBase, r0);
        gemm1_mfma_kernel<<<mtiles * 8, 256, 0, stream>>>(
            XpBase, Wp, b1, hidden);
        head_kernel<<<rows / 4, 256, 0, stream>>>(
            hidden, W2, b2, mask, ra, ctr, flagList, out, r0);
    }

    refine_kernel<<<64, 1024, 0, stream>>>(
        buf_h, stk_h, out_h, act_h, W1, b1, W2, b2, mask, ra, ctr, flagList, out);
}

// Round 6
// 829.825 us; speedup vs baseline: 3.6975x; 3.6975x over previous
//
#include <hip/hip_runtime.h>
#include <math.h>

// TransitionNER head:  hidden = tanh(concat(4x[B,1024]) @ W1 + b1)
//                      logits = hidden @ W2 + b2 ; masked log-softmax ; argmax + gold gather
// B=16384, H=1024, A=20, K=4096.
//
// Round 6: refine fixed after the round-5 spill disaster (1024-thr block forced
// 64 VGPRs -> wa/wb spilled -> 7MB scratch writes, 2.4ms).
//  - refine_hidden: 256-thr blocks, work unit = (row-pair, 256-col chunk);
//    X rows in LDS; depth-2 pipelined W1 column loads (32 regs, no spill);
//    exact f32 hidden rows -> hiddenR (aliases dead Xp region).
//  - refine_head: one wave per flagged row, exact 20-way head from hiddenR.
// gemm/xpack/wpack/head/detect unchanged (proven).

#define BTOT 16384
#define HD   1024
#define NACT 20
#define KTOT 4096
#define KT_N 128          // number of 32-wide k tiles

typedef __attribute__((ext_vector_type(8))) short short8;
typedef __attribute__((ext_vector_type(4))) float f32x4;

#define MFMA(a, b, c) __builtin_amdgcn_mfma_f32_16x16x32_bf16((a), (b), (c), 0, 0, 0)

// ---------------- global -> LDS direct load (16B) ----------------
__device__ __forceinline__ void gload16(const void* g, void* l)
{
    auto gp = (const __attribute__((address_space(1))) unsigned int*)((uintptr_t)g);
    auto lp = (__attribute__((address_space(3))) unsigned int*)((uintptr_t)l);
    __builtin_amdgcn_global_load_lds(gp, lp, 16, 0, 0);
}

// ---------------- bf16 split helpers (RNE) ----------------
__device__ __forceinline__ void split8(const float4 v0, const float4 v1,
                                       int4& hi, int4& lo)
{
    const float f[8] = {v0.x, v0.y, v0.z, v0.w, v1.x, v1.y, v1.z, v1.w};
    unsigned hp[4], lp[4];
#pragma unroll
    for (int i = 0; i < 4; ++i) {
        const unsigned u0 = __float_as_uint(f[2 * i]);
        const unsigned u1 = __float_as_uint(f[2 * i + 1]);
        const unsigned r0 = u0 + 0x7FFFu + ((u0 >> 16) & 1u);
        const unsigned r1 = u1 + 0x7FFFu + ((u1 >> 16) & 1u);
        hp[i] = (r0 >> 16) | (r1 & 0xFFFF0000u);
        const float h0 = __uint_as_float(r0 & 0xFFFF0000u);
        const float h1 = __uint_as_float(r1 & 0xFFFF0000u);
        const float d0 = f[2 * i] - h0;
        const float d1 = f[2 * i + 1] - h1;
        const unsigned s0 = __float_as_uint(d0);
        const unsigned s1 = __float_as_uint(d1);
        const unsigned q0 = s0 + 0x7FFFu + ((s0 >> 16) & 1u);
        const unsigned q1 = s1 + 0x7FFFu + ((s1 >> 16) & 1u);
        lp[i] = (q0 >> 16) | (q1 & 0xFFFF0000u);
    }
    hi = make_int4((int)hp[0], (int)hp[1], (int)hp[2], (int)hp[3]);
    lo = make_int4((int)lp[0], (int)lp[1], (int)lp[2], (int)lp[3]);
}

// ---------------- mask dtype detection ----------------
__global__ __launch_bounds__(256) void detect_mask_kernel(
    const unsigned int* __restrict__ w, int nwords, int* __restrict__ ctr)
{
    int c0 = 0, c1 = 0, c2 = 0, c3 = 0;
    for (int i = blockIdx.x * 256 + threadIdx.x; i < nwords; i += gridDim.x * 256) {
        unsigned int v = w[i];
        c0 += (v & 0x000000FFu) ? 1 : 0;
        c1 += (v & 0x0000FF00u) ? 1 : 0;
        c2 += (v & 0x00FF0000u) ? 1 : 0;
        c3 += (v & 0xFF000000u) ? 1 : 0;
    }
#pragma unroll
    for (int off = 32; off; off >>= 1) {
        c0 += __shfl_xor(c0, off, 64);
        c1 += __shfl_xor(c1, off, 64);
        c2 += __shfl_xor(c2, off, 64);
        c3 += __shfl_xor(c3, off, 64);
    }
    if ((threadIdx.x & 63) == 0) {
        atomicAdd(&ctr[0], c0);
        atomicAdd(&ctr[1], c1);
        atomicAdd(&ctr[2], c2);
        atomicAdd(&ctr[3], c3);
    }
}

// ---------------- X pack: f32 rows -> swizzled bf16 hi/lo tile images ----------------
__global__ __launch_bounds__(256) void xpack_kernel(
    const float* __restrict__ A0, const float* __restrict__ A1,
    const float* __restrict__ A2, const float* __restrict__ A3,
    char* __restrict__ Xp, int rowBase)
{
    const int b  = blockIdx.x;
    const int t  = threadIdx.x;
    const int mt = b >> 6;
    const int kt = ((b & 63) << 1) + (t >> 7);
    const int rr = t & 127;

    const int seg = kt >> 5;
    const float* __restrict__ s =
        (seg == 0) ? A0 : (seg == 1) ? A1 : (seg == 2) ? A2 : A3;
    const float4* sp = (const float4*)(s + (size_t)(rowBase + mt * 128 + rr) * HD
                                         + (kt & 31) * 32);

    int4 hi[4], lo[4];
#pragma unroll
    for (int c = 0; c < 4; ++c)
        split8(sp[2 * c], sp[2 * c + 1], hi[c], lo[c]);

    char* rowp = Xp + (((size_t)(mt * KT_N + kt)) << 14) + rr * 128;
    const int r7 = rr & 7;
#pragma unroll
    for (int c = 0; c < 4; ++c) {
        const int ph = (c ^ r7) << 4;
        *(int4*)(rowp + ph)        = hi[c];
        *(int4*)(rowp + (ph ^ 64)) = lo[c];
    }
}

// ---------------- W pack: [K][N] f32 -> swizzled bf16 hi/lo tile images ----------------
__global__ __launch_bounds__(256) void wpack_kernel(
    const float* __restrict__ W1, char* __restrict__ Wp)
{
    const int b  = blockIdx.x;
    const int t  = threadIdx.x;
    const int nt = b >> 7;
    const int kt = b & 127;
    const int nn = t & 127;
    const int h  = t >> 7;

    float f[16];
#pragma unroll
    for (int kk = 0; kk < 16; ++kk)
        f[kk] = W1[(size_t)(kt * 32 + h * 16 + kk) * HD + nt * 128 + nn];

    int4 hi0, lo0, hi1, lo1;
    split8(make_float4(f[0], f[1], f[2], f[3]),
           make_float4(f[4], f[5], f[6], f[7]), hi0, lo0);
    split8(make_float4(f[8], f[9], f[10], f[11]),
           make_float4(f[12], f[13], f[14], f[15]), hi1, lo1);

    char* rowp = Wp + (((size_t)(nt * KT_N + kt)) << 14) + nn * 128;
    const int r7 = nn & 7;
    const int s0 = ((2 * h) ^ r7) << 4;
    const int s1 = ((2 * h + 1) ^ r7) << 4;
    *(int4*)(rowp + s0)        = hi0;
    *(int4*)(rowp + s1)        = hi1;
    *(int4*)(rowp + (s0 ^ 64)) = lo0;
    *(int4*)(rowp + (s1 ^ 64)) = lo1;
}

// ---------------- GEMM1 (pure MFMA, 3-pass) + bias + tanh ----------------
__global__ __launch_bounds__(256, 2) void gemm1_mfma_kernel(
    const char* __restrict__ Xp, const char* __restrict__ Wp,
    const float* __restrict__ b1, float* __restrict__ hidden)
{
    __shared__ __align__(16) char smem[65536];   // 2 buf x (A 16KB + B 16KB)

    const int nwg = gridDim.x;
    const int q = nwg >> 3;
    const int newbid = (blockIdx.x & 7) * q + (blockIdx.x >> 3);
    const int mt = newbid >> 3;
    const int nt = newbid & 7;

    const int t    = threadIdx.x;
    const int lane = t & 63;
    const int wid  = t >> 6;
    const int wr = wid >> 1, wc = wid & 1;
    const int lrow = lane & 15;
    const int lk   = lane >> 4;

    const char* gA = Xp + (((size_t)mt * KT_N) << 14);
    const char* gB = Wp + (((size_t)nt * KT_N) << 14);

    const int so0 = t << 4;

    const unsigned aOff = (unsigned)(wr * 64 + lrow) * 128 + (((unsigned)lk ^ (unsigned)(lrow & 7)) << 4);
    const unsigned bOff = (unsigned)(wc * 64 + lrow) * 128 + (((unsigned)lk ^ (unsigned)(lrow & 7)) << 4);

    f32x4 acc[4][4];
#pragma unroll
    for (int i = 0; i < 4; ++i)
#pragma unroll
        for (int j = 0; j < 4; ++j) acc[i][j] = (f32x4){0.f, 0.f, 0.f, 0.f};

    // prologue: stage kt=0 into buf 0
#pragma unroll
    for (int i = 0; i < 4; ++i) {
        gload16(gA + so0 + i * 4096, smem + so0 + i * 4096);
        gload16(gB + so0 + i * 4096, smem + 16384 + so0 + i * 4096);
    }
    __syncthreads();

    int cur = 0;
    for (int kt = 0; kt < KT_N; ++kt) {
        if (kt + 1 < KT_N) {
            const char* nA = gA + (((size_t)(kt + 1)) << 14);
            const char* nB = gB + (((size_t)(kt + 1)) << 14);
            char* lA = smem + (cur ^ 1) * 32768;
            char* lB = lA + 16384;
#pragma unroll
            for (int i = 0; i < 4; ++i) {
                gload16(nA + so0 + i * 4096, lA + so0 + i * 4096);
                gload16(nB + so0 + i * 4096, lB + so0 + i * 4096);
            }
        }

        const char* lA = smem + cur * 32768;
        const char* lB = lA + 16384;

        short8 ah[4], al[4], bh[4], bl[4];
#pragma unroll
        for (int f = 0; f < 4; ++f) {
            ah[f] = *(const short8*)(lA + (aOff + f * 2048));
            al[f] = *(const short8*)(lA + ((aOff + f * 2048) ^ 64));
            bh[f] = *(const short8*)(lB + (bOff + f * 2048));
            bl[f] = *(const short8*)(lB + ((bOff + f * 2048) ^ 64));
        }
#pragma unroll
        for (int fi = 0; fi < 4; ++fi)
#pragma unroll
            for (int fj = 0; fj < 4; ++fj)
                acc[fi][fj] = MFMA(ah[fi], bh[fj], acc[fi][fj]);
#pragma unroll
        for (int fi = 0; fi < 4; ++fi)
#pragma unroll
            for (int fj = 0; fj < 4; ++fj)
                acc[fi][fj] = MFMA(ah[fi], bl[fj], acc[fi][fj]);
#pragma unroll
        for (int fi = 0; fi < 4; ++fi)
#pragma unroll
            for (int fj = 0; fj < 4; ++fj)
                acc[fi][fj] = MFMA(al[fi], bh[fj], acc[fi][fj]);

        __syncthreads();
        cur ^= 1;
    }

    // epilogue: bias + tanh
#pragma unroll
    for (int fj = 0; fj < 4; ++fj) {
        const int col = nt * 128 + wc * 64 + fj * 16 + lrow;
        const float bias = b1[col];
#pragma unroll
        for (int fi = 0; fi < 4; ++fi) {
            const int row0 = mt * 128 + wr * 64 + fi * 16 + lk * 4;
#pragma unroll
            for (int r = 0; r < 4; ++r)
                hidden[(size_t)(row0 + r) * HD + col] = tanhf(acc[fi][fj][r] + bias);
        }
    }
}

// ---------------- shared head/refine epilogue ----------------
__device__ __forceinline__ void finish_row(
    const float* __restrict__ acc, const float* __restrict__ b2,
    const void* __restrict__ mask, const int* __restrict__ real_actions,
    int fmt, int row, float* __restrict__ out,
    int* __restrict__ flagCnt, int* __restrict__ flagList, int lane)
{
    float masked[NACT];
#pragma unroll
    for (int a = 0; a < NACT; ++a) {
        const float lg = acc[a] + b2[a];
        bool valid;
        if (fmt == 0)      valid = ((const unsigned char*)mask)[(size_t)row * NACT + a] != 0;
        else if (fmt == 1) valid = ((const int*)mask)[(size_t)row * NACT + a] != 0;
        else               valid = ((const float*)mask)[(size_t)row * NACT + a] != 0.f;
        masked[a] = valid ? lg : -1e9f;
    }
    float m = masked[0], m2 = -3e38f;
    int amax = 0;
#pragma unroll
    for (int a = 1; a < NACT; ++a) {
        const float v = masked[a];
        if (v > m) { m2 = m; m = v; amax = a; }
        else if (v > m2) m2 = v;
    }
    float s = 0.f;
#pragma unroll
    for (int a = 0; a < NACT; ++a) s += expf(masked[a] - m);
    const float lse = m + logf(s);
    const int ga = real_actions[row];
    float gl = masked[0];
#pragma unroll
    for (int a = 1; a < NACT; ++a) gl = (ga == a) ? masked[a] : gl;
    if (lane == 0) {
        out[row] = (float)amax;
        out[BTOT + row] = gl - lse;
        if (flagList != nullptr && (m - m2) < 1e-3f) {
            const int ix = atomicAdd(flagCnt, 1);
            flagList[ix] = row;
        }
    }
}

// ---------------- head: logits, masked log-softmax, argmax, loss, gap-flag ----------------
__global__ __launch_bounds__(256) void head_kernel(
    const float* __restrict__ hidden, const float* __restrict__ W2,
    const float* __restrict__ b2, const void* __restrict__ mask,
    const int* __restrict__ real_actions, int* __restrict__ ctr,
    int* __restrict__ flagList, float* __restrict__ out, int rowBase)
{
    const int lane     = threadIdx.x & 63;
    const int localRow = blockIdx.x * 4 + (threadIdx.x >> 6);
    const int row      = rowBase + localRow;

    float acc[NACT];
#pragma unroll
    for (int a = 0; a < NACT; ++a) acc[a] = 0.f;

    const float* hrow = hidden + (size_t)localRow * HD;
#pragma unroll 4
    for (int j = 0; j < 16; ++j) {
        const int h = lane + 64 * j;
        const float hv = hrow[h];
        const float4* w4 = (const float4*)(W2 + (size_t)h * NACT);
        const float4 w0 = w4[0], w1 = w4[1], w2 = w4[2], w3 = w4[3], w4v = w4[4];
        acc[0]  = fmaf(hv, w0.x,  acc[0]);  acc[1]  = fmaf(hv, w0.y,  acc[1]);
        acc[2]  = fmaf(hv, w0.z,  acc[2]);  acc[3]  = fmaf(hv, w0.w,  acc[3]);
        acc[4]  = fmaf(hv, w1.x,  acc[4]);  acc[5]  = fmaf(hv, w1.y,  acc[5]);
        acc[6]  = fmaf(hv, w1.z,  acc[6]);  acc[7]  = fmaf(hv, w1.w,  acc[7]);
        acc[8]  = fmaf(hv, w2.x,  acc[8]);  acc[9]  = fmaf(hv, w2.y,  acc[9]);
        acc[10] = fmaf(hv, w2.z,  acc[10]); acc[11] = fmaf(hv, w2.w,  acc[11]);
        acc[12] = fmaf(hv, w3.x,  acc[12]); acc[13] = fmaf(hv, w3.y,  acc[13]);
        acc[14] = fmaf(hv, w3.z,  acc[14]); acc[15] = fmaf(hv, w3.w,  acc[15]);
        acc[16] = fmaf(hv, w4v.x, acc[16]); acc[17] = fmaf(hv, w4v.y, acc[17]);
        acc[18] = fmaf(hv, w4v.z, acc[18]); acc[19] = fmaf(hv, w4v.w, acc[19]);
    }
#pragma unroll
    for (int off = 32; off; off >>= 1) {
#pragma unroll
        for (int a = 0; a < NACT; ++a) acc[a] += __shfl_xor(acc[a], off, 64);
    }

    const int c1 = ctr[1], c2 = ctr[2], c3 = ctr[3];
    const int fmt = (c1 > 0) ? 0 : ((c2 > 0 || c3 > 0) ? 2 : 1);

    finish_row(acc, b2, mask, real_actions, fmt, row, out, &ctr[4], flagList, lane);
}

// ---------------- refine pass 1: exact f32 hidden rows for flagged rows ----------------
// work unit u: row-pair p = u>>2, 256-col chunk (u&3). 256 thr, thread = 1 col x 2 rows.
// Depth-2 pipelined W1 loads (wa/wb, 32 regs; 256-thr block -> no VGPR cap).
__global__ __launch_bounds__(256) void refine_hidden_kernel(
    const float* __restrict__ A0, const float* __restrict__ A1,
    const float* __restrict__ A2, const float* __restrict__ A3,
    const float* __restrict__ W1, const float* __restrict__ b1,
    const int* __restrict__ ctr, const int* __restrict__ list,
    float* __restrict__ hiddenR, int cap)
{
    __shared__ float xs[2][KTOT];   // 32 KiB
    const int tid = threadIdx.x;
    int count = ctr[4]; if (count > cap) count = cap;
    const int total = ((count + 1) >> 1) << 2;   // pairs * 4 col-chunks

    for (int u = blockIdx.x; u < total; u += gridDim.x) {
        const int p = u >> 2;
        const int f0 = 2 * p;
        const int f1 = (2 * p + 1 < count) ? (2 * p + 1) : f0;
        const int r0 = list[f0];
        const int r1 = list[f1];
        const int colBase = (u & 3) * 256;

        for (int j = 0; j < 16; ++j) {
            const int i = tid + 256 * j;
            const float* seg = (i < 1024) ? A0 : (i < 2048) ? A1 : (i < 3072) ? A2 : A3;
            xs[0][i] = seg[(size_t)r0 * HD + (i & 1023)];
            xs[1][i] = seg[(size_t)r1 * HD + (i & 1023)];
        }
        __syncthreads();

        const int col = colBase + tid;
        float acc0 = 0.f, acc1 = 0.f;

        float wa[16], wb[16];
#pragma unroll
        for (int v = 0; v < 16; ++v) wa[v] = W1[(size_t)v * HD + col];
#pragma unroll
        for (int v = 0; v < 16; ++v) wb[v] = W1[(size_t)(16 + v) * HD + col];

        for (int k0 = 0; k0 < KTOT; k0 += 32) {
#pragma unroll
            for (int v = 0; v < 16; ++v) {
                acc0 = fmaf(xs[0][k0 + v], wa[v], acc0);
                acc1 = fmaf(xs[1][k0 + v], wa[v], acc1);
            }
            if (k0 + 32 < KTOT) {
#pragma unroll
                for (int v = 0; v < 16; ++v)
                    wa[v] = W1[(size_t)(k0 + 32 + v) * HD + col];
            }
#pragma unroll
            for (int v = 0; v < 16; ++v) {
                acc0 = fmaf(xs[0][k0 + 16 + v], wb[v], acc0);
                acc1 = fmaf(xs[1][k0 + 16 + v], wb[v], acc1);
            }
            if (k0 + 48 < KTOT) {
#pragma unroll
                for (int v = 0; v < 16; ++v)
                    wb[v] = W1[(size_t)(k0 + 48 + v) * HD + col];
            }
        }

        const float bias = b1[col];
        hiddenR[(size_t)f0 * HD + col] = tanhf(acc0 + bias);
        hiddenR[(size_t)f1 * HD + col] = tanhf(acc1 + bias);
        __syncthreads();
    }
}

// ---------------- refine pass 2: exact head for flagged rows ----------------
__global__ __launch_bounds__(256) void refine_head_kernel(
    const float* __restrict__ hiddenR, const float* __restrict__ W2,
    const float* __restrict__ b2, const void* __restrict__ mask,
    const int* __restrict__ real_actions, const int* __restrict__ ctr,
    const int* __restrict__ list, float* __restrict__ out, int cap)
{
    const int lane = threadIdx.x & 63;
    const int wv   = threadIdx.x >> 6;
    int count = ctr[4]; if (count > cap) count = cap;
    const int c1 = ctr[1], c2 = ctr[2], c3 = ctr[3];
    const int fmt = (c1 > 0) ? 0 : ((c2 > 0 || c3 > 0) ? 2 : 1);

    for (int f = blockIdx.x * 4 + wv; f < count; f += gridDim.x * 4) {
        const int row = list[f];
        const float* hrow = hiddenR + (size_t)f * HD;
        float a20[NACT];
#pragma unroll
        for (int a = 0; a < NACT; ++a) a20[a] = 0.f;
#pragma unroll 4
        for (int m = 0; m < 16; ++m) {
            const int h = lane + 64 * m;
            const float hv = hrow[h];
            const float4* w4 = (const float4*)(W2 + (size_t)h * NACT);
            const float4 w0 = w4[0], w1 = w4[1], w2 = w4[2], w3 = w4[3], w4v = w4[4];
            a20[0]  = fmaf(hv, w0.x,  a20[0]);  a20[1]  = fmaf(hv, w0.y,  a20[1]);
            a20[2]  = fmaf(hv, w0.z,  a20[2]);  a20[3]  = fmaf(hv, w0.w,  a20[3]);
            a20[4]  = fmaf(hv, w1.x,  a20[4]);  a20[5]  = fmaf(hv, w1.y,  a20[5]);
            a20[6]  = fmaf(hv, w1.z,  a20[6]);  a20[7]  = fmaf(hv, w1.w,  a20[7]);
            a20[8]  = fmaf(hv, w2.x,  a20[8]);  a20[9]  = fmaf(hv, w2.y,  a20[9]);
            a20[10] = fmaf(hv, w2.z,  a20[10]); a20[11] = fmaf(hv, w2.w,  a20[11]);
            a20[12] = fmaf(hv, w3.x,  a20[12]); a20[13] = fmaf(hv, w3.y,  a20[13]);
            a20[14] = fmaf(hv, w3.z,  a20[14]); a20[15] = fmaf(hv, w3.w,  a20[15]);
            a20[16] = fmaf(hv, w4v.x, a20[16]); a20[17] = fmaf(hv, w4v.y, a20[17]);
            a20[18] = fmaf(hv, w4v.z, a20[18]); a20[19] = fmaf(hv, w4v.w, a20[19]);
        }
#pragma unroll
        for (int off = 32; off; off >>= 1) {
#pragma unroll
            for (int a = 0; a < NACT; ++a) a20[a] += __shfl_xor(a20[a], off, 64);
        }
        finish_row(a20, b2, mask, real_actions, fmt, row, out, nullptr, nullptr, lane);
    }
}

// ---------------- launcher ----------------
extern "C" void kernel_launch(void* const* d_in, const int* in_sizes, int n_in,
                              void* d_out, int out_size, void* d_ws, size_t ws_size,
                              hipStream_t stream)
{
    const float* buf_h = (const float*)d_in[0];
    const float* stk_h = (const float*)d_in[1];
    const float* out_h = (const float*)d_in[2];
    const float* act_h = (const float*)d_in[3];
    const float* W1    = (const float*)d_in[4];
    const float* b1    = (const float*)d_in[5];
    const float* W2    = (const float*)d_in[6];
    const float* b2    = (const float*)d_in[7];
    const void*  mask  = d_in[8];
    const int*   ra    = (const int*)d_in[9];
    float*       out   = (float*)d_out;

    // ws layout:
    //   [0,256)          : ctr (mask byte counters 0..3, flag count at [4])
    //   [256, 256+64K)   : flagged-row list (int[16384])
    //   then 16MB        : Wp tile images (8 nt x 128 kt x 16KB)
    //   then             : Xp chunk tile images (16KB per row) + hidden (4KB per row)
    //                      -- reused after the main pass as hiddenR (4KB per flagged row)
    int*  ctr      = (int*)d_ws;
    int*  flagList = (int*)((char*)d_ws + 256);
    char* Wp       = (char*)d_ws + 256 + 65536;
    const size_t wpBytes = (size_t)8 * KT_N * 16384;           // 16 MiB
    char* XpBase   = Wp + wpBytes;
    const size_t fixed = 256 + 65536 + wpBytes;

    hipMemsetAsync(d_ws, 0, 256, stream);
    detect_mask_kernel<<<64, 256, 0, stream>>>(
        (const unsigned int*)mask, BTOT * NACT / 4, ctr);
    wpack_kernel<<<8 * KT_N, 256, 0, stream>>>(W1, Wp);

    // chunk rows so Xp (16KB/row) + hidden (4KB/row) fit in the workspace
    const size_t perRow = 16384 + 4096;
    const size_t avail  = (ws_size > fixed) ? (ws_size - fixed) : 0;
    long maxRows = (long)(avail / perRow);
    int Bc;
    if (maxRows >= BTOT) Bc = BTOT;
    else {
        Bc = (int)((maxRows / 128) * 128);
        if (Bc <= 0) Bc = 128;
    }
    float* hidden = (float*)(XpBase + (size_t)Bc * 16384);

    for (int r0 = 0; r0 < BTOT; r0 += Bc) {
        const int rows = (BTOT - r0 < Bc) ? (BTOT - r0) : Bc;   // multiple of 128
        const int mtiles = rows / 128;
        xpack_kernel<<<mtiles * 64, 256, 0, stream>>>(
            buf_h, stk_h, out_h, act_h, XpBase, r0);
        gemm1_mfma_kernel<<<mtiles * 8, 256, 0, stream>>>(
            XpBase, Wp, b1, hidden);
        head_kernel<<<rows / 4, 256, 0, stream>>>(
            hidden, W2, b2, mask, ra, ctr, flagList, out, r0);
    }

    // refine: hiddenR aliases the (now dead) Xp+hidden region: Bc*20KB -> Bc*5 rows
    float* hiddenR = (float*)XpBase;
    long capL = ((long)Bc * perRow) / ((size_t)HD * sizeof(float));
    int cap = (capL > BTOT) ? BTOT : (int)capL;

    refine_hidden_kernel<<<1024, 256, 0, stream>>>(
        buf_h, stk_h, out_h, act_h, W1, b1, ctr, flagList, hiddenR, cap);
    refine_head_kernel<<<64, 256, 0, stream>>>(
        hiddenR, W2, b2, mask, ra, ctr, flagList, out, cap);
}

// Round 7
// 729.657 us; speedup vs baseline: 4.2051x; 1.1373x over previous
//
#include <hip/hip_runtime.h>
#include <math.h>

// TransitionNER head:  hidden = tanh(concat(4x[B,1024]) @ W1 + b1)
//                      logits = hidden @ W2 + b2 ; masked log-softmax ; argmax + gold gather
// B=16384, H=1024, A=20, K=4096.
//
// Round 7:
//  - refine_hidden: TLP redesign. unit = (row-pair, 64-col chunk) -> ~16x more
//    blocks (2.8 waves/SIMD) so W1's ~700cyc L3 latency overlaps across waves
//    instead of serializing one starved wave (was ~186us). 4 k-quarter partials
//    per column, LDS-reduced, then tanh.
//  - head_kernel: 2 rows per wave -> each W2 load reused twice (halves W2 L2 traffic).
// gemm/xpack/wpack/detect/refine_head unchanged (proven, separately measurable).

#define BTOT 16384
#define HD   1024
#define NACT 20
#define KTOT 4096
#define KT_N 128          // number of 32-wide k tiles

typedef __attribute__((ext_vector_type(8))) short short8;
typedef __attribute__((ext_vector_type(4))) float f32x4;

#define MFMA(a, b, c) __builtin_amdgcn_mfma_f32_16x16x32_bf16((a), (b), (c), 0, 0, 0)

// ---------------- global -> LDS direct load (16B) ----------------
__device__ __forceinline__ void gload16(const void* g, void* l)
{
    auto gp = (const __attribute__((address_space(1))) unsigned int*)((uintptr_t)g);
    auto lp = (__attribute__((address_space(3))) unsigned int*)((uintptr_t)l);
    __builtin_amdgcn_global_load_lds(gp, lp, 16, 0, 0);
}

// ---------------- bf16 split helpers (RNE) ----------------
__device__ __forceinline__ void split8(const float4 v0, const float4 v1,
                                       int4& hi, int4& lo)
{
    const float f[8] = {v0.x, v0.y, v0.z, v0.w, v1.x, v1.y, v1.z, v1.w};
    unsigned hp[4], lp[4];
#pragma unroll
    for (int i = 0; i < 4; ++i) {
        const unsigned u0 = __float_as_uint(f[2 * i]);
        const unsigned u1 = __float_as_uint(f[2 * i + 1]);
        const unsigned r0 = u0 + 0x7FFFu + ((u0 >> 16) & 1u);
        const unsigned r1 = u1 + 0x7FFFu + ((u1 >> 16) & 1u);
        hp[i] = (r0 >> 16) | (r1 & 0xFFFF0000u);
        const float h0 = __uint_as_float(r0 & 0xFFFF0000u);
        const float h1 = __uint_as_float(r1 & 0xFFFF0000u);
        const float d0 = f[2 * i] - h0;
        const float d1 = f[2 * i + 1] - h1;
        const unsigned s0 = __float_as_uint(d0);
        const unsigned s1 = __float_as_uint(d1);
        const unsigned q0 = s0 + 0x7FFFu + ((s0 >> 16) & 1u);
        const unsigned q1 = s1 + 0x7FFFu + ((s1 >> 16) & 1u);
        lp[i] = (q0 >> 16) | (q1 & 0xFFFF0000u);
    }
    hi = make_int4((int)hp[0], (int)hp[1], (int)hp[2], (int)hp[3]);
    lo = make_int4((int)lp[0], (int)lp[1], (int)lp[2], (int)lp[3]);
}

// ---------------- mask dtype detection ----------------
__global__ __launch_bounds__(256) void detect_mask_kernel(
    const unsigned int* __restrict__ w, int nwords, int* __restrict__ ctr)
{
    int c0 = 0, c1 = 0, c2 = 0, c3 = 0;
    for (int i = blockIdx.x * 256 + threadIdx.x; i < nwords; i += gridDim.x * 256) {
        unsigned int v = w[i];
        c0 += (v & 0x000000FFu) ? 1 : 0;
        c1 += (v & 0x0000FF00u) ? 1 : 0;
        c2 += (v & 0x00FF0000u) ? 1 : 0;
        c3 += (v & 0xFF000000u) ? 1 : 0;
    }
#pragma unroll
    for (int off = 32; off; off >>= 1) {
        c0 += __shfl_xor(c0, off, 64);
        c1 += __shfl_xor(c1, off, 64);
        c2 += __shfl_xor(c2, off, 64);
        c3 += __shfl_xor(c3, off, 64);
    }
    if ((threadIdx.x & 63) == 0) {
        atomicAdd(&ctr[0], c0);
        atomicAdd(&ctr[1], c1);
        atomicAdd(&ctr[2], c2);
        atomicAdd(&ctr[3], c3);
    }
}

// ---------------- X pack: f32 rows -> swizzled bf16 hi/lo tile images ----------------
__global__ __launch_bounds__(256) void xpack_kernel(
    const float* __restrict__ A0, const float* __restrict__ A1,
    const float* __restrict__ A2, const float* __restrict__ A3,
    char* __restrict__ Xp, int rowBase)
{
    const int b  = blockIdx.x;
    const int t  = threadIdx.x;
    const int mt = b >> 6;
    const int kt = ((b & 63) << 1) + (t >> 7);
    const int rr = t & 127;

    const int seg = kt >> 5;
    const float* __restrict__ s =
        (seg == 0) ? A0 : (seg == 1) ? A1 : (seg == 2) ? A2 : A3;
    const float4* sp = (const float4*)(s + (size_t)(rowBase + mt * 128 + rr) * HD
                                         + (kt & 31) * 32);

    int4 hi[4], lo[4];
#pragma unroll
    for (int c = 0; c < 4; ++c)
        split8(sp[2 * c], sp[2 * c + 1], hi[c], lo[c]);

    char* rowp = Xp + (((size_t)(mt * KT_N + kt)) << 14) + rr * 128;
    const int r7 = rr & 7;
#pragma unroll
    for (int c = 0; c < 4; ++c) {
        const int ph = (c ^ r7) << 4;
        *(int4*)(rowp + ph)        = hi[c];
        *(int4*)(rowp + (ph ^ 64)) = lo[c];
    }
}

// ---------------- W pack: [K][N] f32 -> swizzled bf16 hi/lo tile images ----------------
__global__ __launch_bounds__(256) void wpack_kernel(
    const float* __restrict__ W1, char* __restrict__ Wp)
{
    const int b  = blockIdx.x;
    const int t  = threadIdx.x;
    const int nt = b >> 7;
    const int kt = b & 127;
    const int nn = t & 127;
    const int h  = t >> 7;

    float f[16];
#pragma unroll
    for (int kk = 0; kk < 16; ++kk)
        f[kk] = W1[(size_t)(kt * 32 + h * 16 + kk) * HD + nt * 128 + nn];

    int4 hi0, lo0, hi1, lo1;
    split8(make_float4(f[0], f[1], f[2], f[3]),
           make_float4(f[4], f[5], f[6], f[7]), hi0, lo0);
    split8(make_float4(f[8], f[9], f[10], f[11]),
           make_float4(f[12], f[13], f[14], f[15]), hi1, lo1);

    char* rowp = Wp + (((size_t)(nt * KT_N + kt)) << 14) + nn * 128;
    const int r7 = nn & 7;
    const int s0 = ((2 * h) ^ r7) << 4;
    const int s1 = ((2 * h + 1) ^ r7) << 4;
    *(int4*)(rowp + s0)        = hi0;
    *(int4*)(rowp + s1)        = hi1;
    *(int4*)(rowp + (s0 ^ 64)) = lo0;
    *(int4*)(rowp + (s1 ^ 64)) = lo1;
}

// ---------------- GEMM1 (pure MFMA, 3-pass) + bias + tanh ----------------
__global__ __launch_bounds__(256, 2) void gemm1_mfma_kernel(
    const char* __restrict__ Xp, const char* __restrict__ Wp,
    const float* __restrict__ b1, float* __restrict__ hidden)
{
    __shared__ __align__(16) char smem[65536];   // 2 buf x (A 16KB + B 16KB)

    const int nwg = gridDim.x;
    const int q = nwg >> 3;
    const int newbid = (blockIdx.x & 7) * q + (blockIdx.x >> 3);
    const int mt = newbid >> 3;
    const int nt = newbid & 7;

    const int t    = threadIdx.x;
    const int lane = t & 63;
    const int wid  = t >> 6;
    const int wr = wid >> 1, wc = wid & 1;
    const int lrow = lane & 15;
    const int lk   = lane >> 4;

    const char* gA = Xp + (((size_t)mt * KT_N) << 14);
    const char* gB = Wp + (((size_t)nt * KT_N) << 14);

    const int so0 = t << 4;

    const unsigned aOff = (unsigned)(wr * 64 + lrow) * 128 + (((unsigned)lk ^ (unsigned)(lrow & 7)) << 4);
    const unsigned bOff = (unsigned)(wc * 64 + lrow) * 128 + (((unsigned)lk ^ (unsigned)(lrow & 7)) << 4);

    f32x4 acc[4][4];
#pragma unroll
    for (int i = 0; i < 4; ++i)
#pragma unroll
        for (int j = 0; j < 4; ++j) acc[i][j] = (f32x4){0.f, 0.f, 0.f, 0.f};

    // prologue: stage kt=0 into buf 0
#pragma unroll
    for (int i = 0; i < 4; ++i) {
        gload16(gA + so0 + i * 4096, smem + so0 + i * 4096);
        gload16(gB + so0 + i * 4096, smem + 16384 + so0 + i * 4096);
    }
    __syncthreads();

    int cur = 0;
    for (int kt = 0; kt < KT_N; ++kt) {
        if (kt + 1 < KT_N) {
            const char* nA = gA + (((size_t)(kt + 1)) << 14);
            const char* nB = gB + (((size_t)(kt + 1)) << 14);
            char* lA = smem + (cur ^ 1) * 32768;
            char* lB = lA + 16384;
#pragma unroll
            for (int i = 0; i < 4; ++i) {
                gload16(nA + so0 + i * 4096, lA + so0 + i * 4096);
                gload16(nB + so0 + i * 4096, lB + so0 + i * 4096);
            }
        }

        const char* lA = smem + cur * 32768;
        const char* lB = lA + 16384;

        short8 ah[4], al[4], bh[4], bl[4];
#pragma unroll
        for (int f = 0; f < 4; ++f) {
            ah[f] = *(const short8*)(lA + (aOff + f * 2048));
            al[f] = *(const short8*)(lA + ((aOff + f * 2048) ^ 64));
            bh[f] = *(const short8*)(lB + (bOff + f * 2048));
            bl[f] = *(const short8*)(lB + ((bOff + f * 2048) ^ 64));
        }
#pragma unroll
        for (int fi = 0; fi < 4; ++fi)
#pragma unroll
            for (int fj = 0; fj < 4; ++fj)
                acc[fi][fj] = MFMA(ah[fi], bh[fj], acc[fi][fj]);
#pragma unroll
        for (int fi = 0; fi < 4; ++fi)
#pragma unroll
            for (int fj = 0; fj < 4; ++fj)
                acc[fi][fj] = MFMA(ah[fi], bl[fj], acc[fi][fj]);
#pragma unroll
        for (int fi = 0; fi < 4; ++fi)
#pragma unroll
            for (int fj = 0; fj < 4; ++fj)
                acc[fi][fj] = MFMA(al[fi], bh[fj], acc[fi][fj]);

        __syncthreads();
        cur ^= 1;
    }

    // epilogue: bias + tanh
#pragma unroll
    for (int fj = 0; fj < 4; ++fj) {
        const int col = nt * 128 + wc * 64 + fj * 16 + lrow;
        const float bias = b1[col];
#pragma unroll
        for (int fi = 0; fi < 4; ++fi) {
            const int row0 = mt * 128 + wr * 64 + fi * 16 + lk * 4;
#pragma unroll
            for (int r = 0; r < 4; ++r)
                hidden[(size_t)(row0 + r) * HD + col] = tanhf(acc[fi][fj][r] + bias);
        }
    }
}

// ---------------- shared head/refine epilogue ----------------
__device__ __forceinline__ void finish_row(
    const float* __restrict__ acc, const float* __restrict__ b2,
    const void* __restrict__ mask, const int* __restrict__ real_actions,
    int fmt, int row, float* __restrict__ out,
    int* __restrict__ flagCnt, int* __restrict__ flagList, int lane)
{
    float masked[NACT];
#pragma unroll
    for (int a = 0; a < NACT; ++a) {
        const float lg = acc[a] + b2[a];
        bool valid;
        if (fmt == 0)      valid = ((const unsigned char*)mask)[(size_t)row * NACT + a] != 0;
        else if (fmt == 1) valid = ((const int*)mask)[(size_t)row * NACT + a] != 0;
        else               valid = ((const float*)mask)[(size_t)row * NACT + a] != 0.f;
        masked[a] = valid ? lg : -1e9f;
    }
    float m = masked[0], m2 = -3e38f;
    int amax = 0;
#pragma unroll
    for (int a = 1; a < NACT; ++a) {
        const float v = masked[a];
        if (v > m) { m2 = m; m = v; amax = a; }
        else if (v > m2) m2 = v;
    }
    float s = 0.f;
#pragma unroll
    for (int a = 0; a < NACT; ++a) s += expf(masked[a] - m);
    const float lse = m + logf(s);
    const int ga = real_actions[row];
    float gl = masked[0];
#pragma unroll
    for (int a = 1; a < NACT; ++a) gl = (ga == a) ? masked[a] : gl;
    if (lane == 0) {
        out[row] = (float)amax;
        out[BTOT + row] = gl - lse;
        if (flagList != nullptr && (m - m2) < 1e-3f) {
            const int ix = atomicAdd(flagCnt, 1);
            flagList[ix] = row;
        }
    }
}

// ---------------- head: 2 rows per wave (W2 loads reused) ----------------
// grid = rows/8 blocks of 256 (4 waves x 2 rows).
__global__ __launch_bounds__(256) void head_kernel(
    const float* __restrict__ hidden, const float* __restrict__ W2,
    const float* __restrict__ b2, const void* __restrict__ mask,
    const int* __restrict__ real_actions, int* __restrict__ ctr,
    int* __restrict__ flagList, float* __restrict__ out, int rowBase)
{
    const int lane = threadIdx.x & 63;
    const int lr0  = (blockIdx.x * 4 + (threadIdx.x >> 6)) * 2;  // chunk-local row pair

    float a0[NACT], a1[NACT];
#pragma unroll
    for (int a = 0; a < NACT; ++a) { a0[a] = 0.f; a1[a] = 0.f; }

    const float* h0 = hidden + (size_t)lr0 * HD;
    const float* h1 = h0 + HD;
#pragma unroll 4
    for (int j = 0; j < 16; ++j) {
        const int h = lane + 64 * j;
        const float hv0 = h0[h];
        const float hv1 = h1[h];
        const float4* w4 = (const float4*)(W2 + (size_t)h * NACT);
        const float4 w0 = w4[0], w1 = w4[1], w2 = w4[2], w3 = w4[3], w4v = w4[4];
        a0[0]  = fmaf(hv0, w0.x,  a0[0]);  a1[0]  = fmaf(hv1, w0.x,  a1[0]);
        a0[1]  = fmaf(hv0, w0.y,  a0[1]);  a1[1]  = fmaf(hv1, w0.y,  a1[1]);
        a0[2]  = fmaf(hv0, w0.z,  a0[2]);  a1[2]  = fmaf(hv1, w0.z,  a1[2]);
        a0[3]  = fmaf(hv0, w0.w,  a0[3]);  a1[3]  = fmaf(hv1, w0.w,  a1[3]);
        a0[4]  = fmaf(hv0, w1.x,  a0[4]);  a1[4]  = fmaf(hv1, w1.x,  a1[4]);
        a0[5]  = fmaf(hv0, w1.y,  a0[5]);  a1[5]  = fmaf(hv1, w1.y,  a1[5]);
        a0[6]  = fmaf(hv0, w1.z,  a0[6]);  a1[6]  = fmaf(hv1, w1.z,  a1[6]);
        a0[7]  = fmaf(hv0, w1.w,  a0[7]);  a1[7]  = fmaf(hv1, w1.w,  a1[7]);
        a0[8]  = fmaf(hv0, w2.x,  a0[8]);  a1[8]  = fmaf(hv1, w2.x,  a1[8]);
        a0[9]  = fmaf(hv0, w2.y,  a0[9]);  a1[9]  = fmaf(hv1, w2.y,  a1[9]);
        a0[10] = fmaf(hv0, w2.z,  a0[10]); a1[10] = fmaf(hv1, w2.z,  a1[10]);
        a0[11] = fmaf(hv0, w2.w,  a0[11]); a1[11] = fmaf(hv1, w2.w,  a1[11]);
        a0[12] = fmaf(hv0, w3.x,  a0[12]); a1[12] = fmaf(hv1, w3.x,  a1[12]);
        a0[13] = fmaf(hv0, w3.y,  a0[13]); a1[13] = fmaf(hv1, w3.y,  a1[13]);
        a0[14] = fmaf(hv0, w3.z,  a0[14]); a1[14] = fmaf(hv1, w3.z,  a1[14]);
        a0[15] = fmaf(hv0, w3.w,  a0[15]); a1[15] = fmaf(hv1, w3.w,  a1[15]);
        a0[16] = fmaf(hv0, w4v.x, a0[16]); a1[16] = fmaf(hv1, w4v.x, a1[16]);
        a0[17] = fmaf(hv0, w4v.y, a0[17]); a1[17] = fmaf(hv1, w4v.y, a1[17]);
        a0[18] = fmaf(hv0, w4v.z, a0[18]); a1[18] = fmaf(hv1, w4v.z, a1[18]);
        a0[19] = fmaf(hv0, w4v.w, a0[19]); a1[19] = fmaf(hv1, w4v.w, a1[19]);
    }
#pragma unroll
    for (int off = 32; off; off >>= 1) {
#pragma unroll
        for (int a = 0; a < NACT; ++a) {
            a0[a] += __shfl_xor(a0[a], off, 64);
            a1[a] += __shfl_xor(a1[a], off, 64);
        }
    }

    const int c1 = ctr[1], c2 = ctr[2], c3 = ctr[3];
    const int fmt = (c1 > 0) ? 0 : ((c2 > 0 || c3 > 0) ? 2 : 1);

    finish_row(a0, b2, mask, real_actions, fmt, rowBase + lr0,     out, &ctr[4], flagList, lane);
    finish_row(a1, b2, mask, real_actions, fmt, rowBase + lr0 + 1, out, &ctr[4], flagList, lane);
}

// ---------------- refine pass 1: exact f32 hidden rows (TLP redesign) ----------------
// unit u = (row-pair p = u>>4, 64-col chunk u&15); 256 thr = 64 cols x 4 k-quarters.
// Per thread: 1024-k partial dot for 2 rows, depth-2 pipelined W1 loads; LDS reduce.
__global__ __launch_bounds__(256) void refine_hidden_kernel(
    const float* __restrict__ A0, const float* __restrict__ A1,
    const float* __restrict__ A2, const float* __restrict__ A3,
    const float* __restrict__ W1, const float* __restrict__ b1,
    const int* __restrict__ ctr, const int* __restrict__ list,
    float* __restrict__ hiddenR, int cap)
{
    __shared__ float xs[2][KTOT];      // 32 KiB
    __shared__ float red[2][4][64];    // 2 KiB
    const int tid = threadIdx.x;
    int count = ctr[4]; if (count > cap) count = cap;
    const int total = ((count + 1) >> 1) << 4;   // pairs * 16 col-chunks

    for (int u = blockIdx.x; u < total; u += gridDim.x) {
        const int p  = u >> 4;
        const int f0 = 2 * p;
        const int f1 = (2 * p + 1 < count) ? (2 * p + 1) : f0;
        const int r0 = list[f0];
        const int r1 = list[f1];
        const int colBase = (u & 15) << 6;

        for (int i = tid; i < KTOT; i += 256) {
            const float* seg = (i < 1024) ? A0 : (i < 2048) ? A1 : (i < 3072) ? A2 : A3;
            xs[0][i] = seg[(size_t)r0 * HD + (i & 1023)];
            xs[1][i] = seg[(size_t)r1 * HD + (i & 1023)];
        }
        __syncthreads();

        const int col   = colBase + (tid & 63);
        const int kbase = (tid >> 6) << 10;     // k-quarter [kbase, kbase+1024)
        const float* Wc = W1 + col;
        float acc0 = 0.f, acc1 = 0.f;

        float wa[16], wb[16];
#pragma unroll
        for (int v = 0; v < 16; ++v) wa[v] = Wc[(size_t)(kbase + v) * HD];
#pragma unroll
        for (int v = 0; v < 16; ++v) wb[v] = Wc[(size_t)(kbase + 16 + v) * HD];

        const int kend = kbase + 1024;
        for (int k0 = kbase; k0 < kend; k0 += 32) {
#pragma unroll
            for (int v = 0; v < 16; ++v) {
                acc0 = fmaf(xs[0][k0 + v], wa[v], acc0);
                acc1 = fmaf(xs[1][k0 + v], wa[v], acc1);
            }
            if (k0 + 32 < kend) {
#pragma unroll
                for (int v = 0; v < 16; ++v)
                    wa[v] = Wc[(size_t)(k0 + 32 + v) * HD];
            }
#pragma unroll
            for (int v = 0; v < 16; ++v) {
                acc0 = fmaf(xs[0][k0 + 16 + v], wb[v], acc0);
                acc1 = fmaf(xs[1][k0 + 16 + v], wb[v], acc1);
            }
            if (k0 + 48 < kend) {
#pragma unroll
                for (int v = 0; v < 16; ++v)
                    wb[v] = Wc[(size_t)(k0 + 48 + v) * HD];
            }
        }

        red[0][tid >> 6][tid & 63] = acc0;
        red[1][tid >> 6][tid & 63] = acc1;
        __syncthreads();

        if (tid < 128) {
            const int r = tid >> 6, c = tid & 63;
            const float s = red[r][0][c] + red[r][1][c] + red[r][2][c] + red[r][3][c];
            const int f = r ? f1 : f0;
            hiddenR[(size_t)f * HD + colBase + c] = tanhf(s + b1[colBase + c]);
        }
        __syncthreads();
    }
}

// ---------------- refine pass 2: exact head for flagged rows ----------------
__global__ __launch_bounds__(256) void refine_head_kernel(
    const float* __restrict__ hiddenR, const float* __restrict__ W2,
    const float* __restrict__ b2, const void* __restrict__ mask,
    const int* __restrict__ real_actions, const int* __restrict__ ctr,
    const int* __restrict__ list, float* __restrict__ out, int cap)
{
    const int lane = threadIdx.x & 63;
    const int wv   = threadIdx.x >> 6;
    int count = ctr[4]; if (count > cap) count = cap;
    const int c1 = ctr[1], c2 = ctr[2], c3 = ctr[3];
    const int fmt = (c1 > 0) ? 0 : ((c2 > 0 || c3 > 0) ? 2 : 1);

    for (int f = blockIdx.x * 4 + wv; f < count; f += gridDim.x * 4) {
        const int row = list[f];
        const float* hrow = hiddenR + (size_t)f * HD;
        float a20[NACT];
#pragma unroll
        for (int a = 0; a < NACT; ++a) a20[a] = 0.f;
#pragma unroll 4
        for (int m = 0; m < 16; ++m) {
            const int h = lane + 64 * m;
            const float hv = hrow[h];
            const float4* w4 = (const float4*)(W2 + (size_t)h * NACT);
            const float4 w0 = w4[0], w1 = w4[1], w2 = w4[2], w3 = w4[3], w4v = w4[4];
            a20[0]  = fmaf(hv, w0.x,  a20[0]);  a20[1]  = fmaf(hv, w0.y,  a20[1]);
            a20[2]  = fmaf(hv, w0.z,  a20[2]);  a20[3]  = fmaf(hv, w0.w,  a20[3]);
            a20[4]  = fmaf(hv, w1.x,  a20[4]);  a20[5]  = fmaf(hv, w1.y,  a20[5]);
            a20[6]  = fmaf(hv, w1.z,  a20[6]);  a20[7]  = fmaf(hv, w1.w,  a20[7]);
            a20[8]  = fmaf(hv, w2.x,  a20[8]);  a20[9]  = fmaf(hv, w2.y,  a20[9]);
            a20[10] = fmaf(hv, w2.z,  a20[10]); a20[11] = fmaf(hv, w2.w,  a20[11]);
            a20[12] = fmaf(hv, w3.x,  a20[12]); a20[13] = fmaf(hv, w3.y,  a20[13]);
            a20[14] = fmaf(hv, w3.z,  a20[14]); a20[15] = fmaf(hv, w3.w,  a20[15]);
            a20[16] = fmaf(hv, w4v.x, a20[16]); a20[17] = fmaf(hv, w4v.y, a20[17]);
            a20[18] = fmaf(hv, w4v.z, a20[18]); a20[19] = fmaf(hv, w4v.w, a20[19]);
        }
#pragma unroll
        for (int off = 32; off; off >>= 1) {
#pragma unroll
            for (int a = 0; a < NACT; ++a) a20[a] += __shfl_xor(a20[a], off, 64);
        }
        finish_row(a20, b2, mask, real_actions, fmt, row, out, nullptr, nullptr, lane);
    }
}

// ---------------- launcher ----------------
extern "C" void kernel_launch(void* const* d_in, const int* in_sizes, int n_in,
                              void* d_out, int out_size, void* d_ws, size_t ws_size,
                              hipStream_t stream)
{
    const float* buf_h = (const float*)d_in[0];
    const float* stk_h = (const float*)d_in[1];
    const float* out_h = (const float*)d_in[2];
    const float* act_h = (const float*)d_in[3];
    const float* W1    = (const float*)d_in[4];
    const float* b1    = (const float*)d_in[5];
    const float* W2    = (const float*)d_in[6];
    const float* b2    = (const float*)d_in[7];
    const void*  mask  = d_in[8];
    const int*   ra    = (const int*)d_in[9];
    float*       out   = (float*)d_out;

    // ws layout:
    //   [0,256)          : ctr (mask byte counters 0..3, flag count at [4])
    //   [256, 256+64K)   : flagged-row list (int[16384])
    //   then 16MB        : Wp tile images (8 nt x 128 kt x 16KB)
    //   then             : Xp chunk tile images (16KB per row) + hidden (4KB per row)
    //                      -- reused after the main pass as hiddenR (4KB per flagged row)
    int*  ctr      = (int*)d_ws;
    int*  flagList = (int*)((char*)d_ws + 256);
    char* Wp       = (char*)d_ws + 256 + 65536;
    const size_t wpBytes = (size_t)8 * KT_N * 16384;           // 16 MiB
    char* XpBase   = Wp + wpBytes;
    const size_t fixed = 256 + 65536 + wpBytes;

    hipMemsetAsync(d_ws, 0, 256, stream);
    detect_mask_kernel<<<64, 256, 0, stream>>>(
        (const unsigned int*)mask, BTOT * NACT / 4, ctr);
    wpack_kernel<<<8 * KT_N, 256, 0, stream>>>(W1, Wp);

    // chunk rows so Xp (16KB/row) + hidden (4KB/row) fit in the workspace
    const size_t perRow = 16384 + 4096;
    const size_t avail  = (ws_size > fixed) ? (ws_size - fixed) : 0;
    long maxRows = (long)(avail / perRow);
    int Bc;
    if (maxRows >= BTOT) Bc = BTOT;
    else {
        Bc = (int)((maxRows / 128) * 128);
        if (Bc <= 0) Bc = 128;
    }
    float* hidden = (float*)(XpBase + (size_t)Bc * 16384);

    for (int r0 = 0; r0 < BTOT; r0 += Bc) {
        const int rows = (BTOT - r0 < Bc) ? (BTOT - r0) : Bc;   // multiple of 128
        const int mtiles = rows / 128;
        xpack_kernel<<<mtiles * 64, 256, 0, stream>>>(
            buf_h, stk_h, out_h, act_h, XpBase, r0);
        gemm1_mfma_kernel<<<mtiles * 8, 256, 0, stream>>>(
            XpBase, Wp, b1, hidden);
        head_kernel<<<rows / 8, 256, 0, stream>>>(
            hidden, W2, b2, mask, ra, ctr, flagList, out, r0);
    }

    // refine: hiddenR aliases the (now dead) Xp+hidden region
    float* hiddenR = (float*)XpBase;
    long capL = ((long)Bc * perRow) / ((size_t)HD * sizeof(float));
    int cap = (capL > BTOT) ? BTOT : (int)capL;

    refine_hidden_kernel<<<2048, 256, 0, stream>>>(
        buf_h, stk_h, out_h, act_h, W1, b1, ctr, flagList, hiddenR, cap);
    refine_head_kernel<<<64, 256, 0, stream>>>(
        hiddenR, W2, b2, mask, ra, ctr, flagList, out, cap);
}

// Round 8
// 550.555 us; speedup vs baseline: 5.5731x; 1.3253x over previous
//
#include <hip/hip_runtime.h>
#include <math.h>

// TransitionNER head:  hidden = tanh(concat(4x[B,1024]) @ W1 + b1)
//                      logits = hidden @ W2 + b2 ; masked log-softmax ; argmax + gold gather
// B=16384, H=1024, A=20, K=4096.
//
// Round 8: gemm was memory-BW bound (~6 TB/s aggregate on 2x2GB of tile traffic,
// 128^2 tile). New gemm: 256x256 tile, 8 waves (512 thr), single dispatch over all
// 16384 rows (grid 64x4 = 256 blocks = 1/CU):
//  - A read as raw f32 (same bytes as packed hi/lo!) -> xpack + Xp + chunking deleted
//  - A staged global->reg->split8->swizzled ds_write (reg prefetch over MFMA)
//  - B staged via global_load_lds from pre-swizzled Wp images (proven)
//  - 128KB double-buffered dynamic LDS; 1 barrier per K-step; 3-pass MFMA
// head/refine/wpack/detect unchanged (proven).

#define BTOT 16384
#define HD   1024
#define NACT 20
#define KTOT 4096
#define KT_N 128          // number of 32-wide k tiles

typedef __attribute__((ext_vector_type(8))) short short8;
typedef __attribute__((ext_vector_type(4))) float f32x4;

#define MFMA(a, b, c) __builtin_amdgcn_mfma_f32_16x16x32_bf16((a), (b), (c), 0, 0, 0)

// ---------------- global -> LDS direct load (16B) ----------------
__device__ __forceinline__ void gload16(const void* g, void* l)
{
    auto gp = (const __attribute__((address_space(1))) unsigned int*)((uintptr_t)g);
    auto lp = (__attribute__((address_space(3))) unsigned int*)((uintptr_t)l);
    __builtin_amdgcn_global_load_lds(gp, lp, 16, 0, 0);
}

// ---------------- bf16 split helpers (RNE) ----------------
__device__ __forceinline__ void split8(const float4 v0, const float4 v1,
                                       int4& hi, int4& lo)
{
    const float f[8] = {v0.x, v0.y, v0.z, v0.w, v1.x, v1.y, v1.z, v1.w};
    unsigned hp[4], lp[4];
#pragma unroll
    for (int i = 0; i < 4; ++i) {
        const unsigned u0 = __float_as_uint(f[2 * i]);
        const unsigned u1 = __float_as_uint(f[2 * i + 1]);
        const unsigned r0 = u0 + 0x7FFFu + ((u0 >> 16) & 1u);
        const unsigned r1 = u1 + 0x7FFFu + ((u1 >> 16) & 1u);
        hp[i] = (r0 >> 16) | (r1 & 0xFFFF0000u);
        const float h0 = __uint_as_float(r0 & 0xFFFF0000u);
        const float h1 = __uint_as_float(r1 & 0xFFFF0000u);
        const float d0 = f[2 * i] - h0;
        const float d1 = f[2 * i + 1] - h1;
        const unsigned s0 = __float_as_uint(d0);
        const unsigned s1 = __float_as_uint(d1);
        const unsigned q0 = s0 + 0x7FFFu + ((s0 >> 16) & 1u);
        const unsigned q1 = s1 + 0x7FFFu + ((s1 >> 16) & 1u);
        lp[i] = (q0 >> 16) | (q1 & 0xFFFF0000u);
    }
    hi = make_int4((int)hp[0], (int)hp[1], (int)hp[2], (int)hp[3]);
    lo = make_int4((int)lp[0], (int)lp[1], (int)lp[2], (int)lp[3]);
}

// ---------------- mask dtype detection ----------------
__global__ __launch_bounds__(256) void detect_mask_kernel(
    const unsigned int* __restrict__ w, int nwords, int* __restrict__ ctr)
{
    int c0 = 0, c1 = 0, c2 = 0, c3 = 0;
    for (int i = blockIdx.x * 256 + threadIdx.x; i < nwords; i += gridDim.x * 256) {
        unsigned int v = w[i];
        c0 += (v & 0x000000FFu) ? 1 : 0;
        c1 += (v & 0x0000FF00u) ? 1 : 0;
        c2 += (v & 0x00FF0000u) ? 1 : 0;
        c3 += (v & 0xFF000000u) ? 1 : 0;
    }
#pragma unroll
    for (int off = 32; off; off >>= 1) {
        c0 += __shfl_xor(c0, off, 64);
        c1 += __shfl_xor(c1, off, 64);
        c2 += __shfl_xor(c2, off, 64);
        c3 += __shfl_xor(c3, off, 64);
    }
    if ((threadIdx.x & 63) == 0) {
        atomicAdd(&ctr[0], c0);
        atomicAdd(&ctr[1], c1);
        atomicAdd(&ctr[2], c2);
        atomicAdd(&ctr[3], c3);
    }
}

// ---------------- W pack: [K][N] f32 -> swizzled bf16 hi/lo tile images ----------------
__global__ __launch_bounds__(256) void wpack_kernel(
    const float* __restrict__ W1, char* __restrict__ Wp)
{
    const int b  = blockIdx.x;
    const int t  = threadIdx.x;
    const int nt = b >> 7;
    const int kt = b & 127;
    const int nn = t & 127;
    const int h  = t >> 7;

    float f[16];
#pragma unroll
    for (int kk = 0; kk < 16; ++kk)
        f[kk] = W1[(size_t)(kt * 32 + h * 16 + kk) * HD + nt * 128 + nn];

    int4 hi0, lo0, hi1, lo1;
    split8(make_float4(f[0], f[1], f[2], f[3]),
           make_float4(f[4], f[5], f[6], f[7]), hi0, lo0);
    split8(make_float4(f[8], f[9], f[10], f[11]),
           make_float4(f[12], f[13], f[14], f[15]), hi1, lo1);

    char* rowp = Wp + (((size_t)(nt * KT_N + kt)) << 14) + nn * 128;
    const int r7 = nn & 7;
    const int s0 = ((2 * h) ^ r7) << 4;
    const int s1 = ((2 * h + 1) ^ r7) << 4;
    *(int4*)(rowp + s0)        = hi0;
    *(int4*)(rowp + s1)        = hi1;
    *(int4*)(rowp + (s0 ^ 64)) = lo0;
    *(int4*)(rowp + (s1 ^ 64)) = lo1;
}

// ---------------- GEMM1: 256x256 tile, 8 waves, 3-pass MFMA + bias + tanh ----------------
// grid = 64 mt x 4 nt = 256 blocks (1/CU). LDS 128KB dynamic: [buf][A 32K | B 32K].
__global__ __launch_bounds__(512, 1) void gemm1_mfma_kernel(
    const float* __restrict__ A0, const float* __restrict__ A1,
    const float* __restrict__ A2, const float* __restrict__ A3,
    const char* __restrict__ Wp, const float* __restrict__ b1,
    float* __restrict__ hidden)
{
    extern __shared__ __align__(16) char smem[];   // 131072

    // XCD-chunked bijective swizzle (nwg = 256, %8 == 0)
    const int newbid = (blockIdx.x & 7) * 32 + (blockIdx.x >> 3);
    const int mt = newbid >> 2;
    const int nt = newbid & 3;

    const int t    = threadIdx.x;
    const int lane = t & 63;
    const int wid  = t >> 6;          // 0..7
    const int wr = wid >> 2, wc = wid & 3;   // 2 x 4 waves, wave tile 128x64
    const int lrow = lane & 15;
    const int lk   = lane >> 4;

    // A staging: thread -> (rowL = t>>1 in 0..255, khalf = t&1)
    const int rowL  = t >> 1;
    const int khalf = t & 1;
    const size_t aRowOff = (size_t)(mt * 256 + rowL) * HD;

    // B staging: two pre-swizzled Wp images per 256-col tile
    const char* gB0 = Wp + (((size_t)((nt * 2)     * KT_N)) << 14);
    const char* gB1 = Wp + (((size_t)((nt * 2 + 1) * KT_N)) << 14);

    // fragment read byte offsets (same swizzle algebra as wpack / A-writes)
    const unsigned aBase = (unsigned)(wr * 128 + lrow) * 128
                         + (((unsigned)lk ^ (unsigned)(lrow & 7)) << 4);
    const unsigned bBase = (unsigned)(wc >> 1) * 16384
                         + (unsigned)((wc & 1) * 64 + lrow) * 128
                         + (((unsigned)lk ^ (unsigned)(lrow & 7)) << 4);

    // A write byte offsets (chunks c = 2*khalf, 2*khalf+1; phys = logical ^ (row&7))
    const int r7 = rowL & 7;
    const unsigned wA0 = (unsigned)rowL * 128 + (((unsigned)(2 * khalf)     ^ (unsigned)r7) << 4);
    const unsigned wA1 = (unsigned)rowL * 128 + (((unsigned)(2 * khalf + 1) ^ (unsigned)r7) << 4);

    f32x4 acc[8][4];
#pragma unroll
    for (int i = 0; i < 8; ++i)
#pragma unroll
        for (int j = 0; j < 4; ++j) acc[i][j] = (f32x4){0.f, 0.f, 0.f, 0.f};

    // ---- prologue: stage kt = 0 into buf 0 ----
    {
        const float4* ap = (const float4*)(A0 + aRowOff + khalf * 16);
        const float4 f0 = ap[0], f1 = ap[1], f2 = ap[2], f3 = ap[3];
        int4 h0, l0, h1, l1;
        split8(f0, f1, h0, l0);
        split8(f2, f3, h1, l1);
        char* lA = smem;
        *(int4*)(lA + wA0)        = h0;
        *(int4*)(lA + (wA0 ^ 64)) = l0;
        *(int4*)(lA + wA1)        = h1;
        *(int4*)(lA + (wA1 ^ 64)) = l1;
        char* lB = smem + 32768;
        gload16(gB0 + t * 16,        lB + t * 16);
        gload16(gB0 + 8192 + t * 16, lB + 8192 + t * 16);
        gload16(gB1 + t * 16,        lB + 16384 + t * 16);
        gload16(gB1 + 8192 + t * 16, lB + 24576 + t * 16);
    }
    __syncthreads();

    int cur = 0;
    for (int kt = 0; kt < KT_N; ++kt) {
        float4 f0, f1, f2, f3;
        const bool pref = (kt + 1 < KT_N);
        if (pref) {
            // issue B global_load_lds into buf^1 (in flight across the MFMAs)
            char* lB = smem + (cur ^ 1) * 65536 + 32768;
            const char* s0 = gB0 + (((size_t)(kt + 1)) << 14);
            const char* s1 = gB1 + (((size_t)(kt + 1)) << 14);
            gload16(s0 + t * 16,        lB + t * 16);
            gload16(s0 + 8192 + t * 16, lB + 8192 + t * 16);
            gload16(s1 + t * 16,        lB + 16384 + t * 16);
            gload16(s1 + 8192 + t * 16, lB + 24576 + t * 16);
            // issue A f32 loads -> regs (consumed after the MFMAs)
            const int kg = (kt + 1) * 32 + khalf * 16;
            const float* seg = (kg < 1024) ? A0 : (kg < 2048) ? A1 : (kg < 3072) ? A2 : A3;
            const float4* ap = (const float4*)(seg + aRowOff + (kg & 1023));
            f0 = ap[0]; f1 = ap[1]; f2 = ap[2]; f3 = ap[3];
        }

        const char* lA = smem + cur * 65536;
        const char* lB = lA + 32768;

        short8 bh[4], bl[4];
#pragma unroll
        for (int nf = 0; nf < 4; ++nf) {
            bh[nf] = *(const short8*)(lB + (bBase + nf * 2048));
            bl[nf] = *(const short8*)(lB + ((bBase + nf * 2048) ^ 64));
        }
#pragma unroll
        for (int mf = 0; mf < 8; ++mf) {
            const short8 ah = *(const short8*)(lA + (aBase + mf * 2048));
            const short8 al = *(const short8*)(lA + ((aBase + mf * 2048) ^ 64));
#pragma unroll
            for (int nf = 0; nf < 4; ++nf) {
                acc[mf][nf] = MFMA(ah, bh[nf], acc[mf][nf]);
                acc[mf][nf] = MFMA(ah, bl[nf], acc[mf][nf]);
                acc[mf][nf] = MFMA(al, bh[nf], acc[mf][nf]);
            }
        }

        if (pref) {
            int4 h0, l0, h1, l1;
            split8(f0, f1, h0, l0);
            split8(f2, f3, h1, l1);
            char* wAp = smem + (cur ^ 1) * 65536;
            *(int4*)(wAp + wA0)        = h0;
            *(int4*)(wAp + (wA0 ^ 64)) = l0;
            *(int4*)(wAp + wA1)        = h1;
            *(int4*)(wAp + (wA1 ^ 64)) = l1;
        }
        __syncthreads();
        cur ^= 1;
    }

    // ---- epilogue: bias + tanh (D: col = lane&15, row = lk*4 + r) ----
#pragma unroll
    for (int nf = 0; nf < 4; ++nf) {
        const int col = nt * 256 + wc * 64 + nf * 16 + lrow;
        const float bias = b1[col];
#pragma unroll
        for (int mf = 0; mf < 8; ++mf) {
            const int row0 = mt * 256 + wr * 128 + mf * 16 + lk * 4;
#pragma unroll
            for (int r = 0; r < 4; ++r)
                hidden[(size_t)(row0 + r) * HD + col] = tanhf(acc[mf][nf][r] + bias);
        }
    }
}

// ---------------- shared head/refine epilogue ----------------
__device__ __forceinline__ void finish_row(
    const float* __restrict__ acc, const float* __restrict__ b2,
    const void* __restrict__ mask, const int* __restrict__ real_actions,
    int fmt, int row, float* __restrict__ out,
    int* __restrict__ flagCnt, int* __restrict__ flagList, int lane)
{
    float masked[NACT];
#pragma unroll
    for (int a = 0; a < NACT; ++a) {
        const float lg = acc[a] + b2[a];
        bool valid;
        if (fmt == 0)      valid = ((const unsigned char*)mask)[(size_t)row * NACT + a] != 0;
        else if (fmt == 1) valid = ((const int*)mask)[(size_t)row * NACT + a] != 0;
        else               valid = ((const float*)mask)[(size_t)row * NACT + a] != 0.f;
        masked[a] = valid ? lg : -1e9f;
    }
    float m = masked[0], m2 = -3e38f;
    int amax = 0;
#pragma unroll
    for (int a = 1; a < NACT; ++a) {
        const float v = masked[a];
        if (v > m) { m2 = m; m = v; amax = a; }
        else if (v > m2) m2 = v;
    }
    float s = 0.f;
#pragma unroll
    for (int a = 0; a < NACT; ++a) s += expf(masked[a] - m);
    const float lse = m + logf(s);
    const int ga = real_actions[row];
    float gl = masked[0];
#pragma unroll
    for (int a = 1; a < NACT; ++a) gl = (ga == a) ? masked[a] : gl;
    if (lane == 0) {
        out[row] = (float)amax;
        out[BTOT + row] = gl - lse;
        if (flagList != nullptr && (m - m2) < 1e-3f) {
            const int ix = atomicAdd(flagCnt, 1);
            flagList[ix] = row;
        }
    }
}

// ---------------- head: 2 rows per wave (W2 loads reused) ----------------
__global__ __launch_bounds__(256) void head_kernel(
    const float* __restrict__ hidden, const float* __restrict__ W2,
    const float* __restrict__ b2, const void* __restrict__ mask,
    const int* __restrict__ real_actions, int* __restrict__ ctr,
    int* __restrict__ flagList, float* __restrict__ out, int rowBase)
{
    const int lane = threadIdx.x & 63;
    const int lr0  = (blockIdx.x * 4 + (threadIdx.x >> 6)) * 2;

    float a0[NACT], a1[NACT];
#pragma unroll
    for (int a = 0; a < NACT; ++a) { a0[a] = 0.f; a1[a] = 0.f; }

    const float* h0 = hidden + (size_t)lr0 * HD;
    const float* h1 = h0 + HD;
#pragma unroll 4
    for (int j = 0; j < 16; ++j) {
        const int h = lane + 64 * j;
        const float hv0 = h0[h];
        const float hv1 = h1[h];
        const float4* w4 = (const float4*)(W2 + (size_t)h * NACT);
        const float4 w0 = w4[0], w1 = w4[1], w2 = w4[2], w3 = w4[3], w4v = w4[4];
        a0[0]  = fmaf(hv0, w0.x,  a0[0]);  a1[0]  = fmaf(hv1, w0.x,  a1[0]);
        a0[1]  = fmaf(hv0, w0.y,  a0[1]);  a1[1]  = fmaf(hv1, w0.y,  a1[1]);
        a0[2]  = fmaf(hv0, w0.z,  a0[2]);  a1[2]  = fmaf(hv1, w0.z,  a1[2]);
        a0[3]  = fmaf(hv0, w0.w,  a0[3]);  a1[3]  = fmaf(hv1, w0.w,  a1[3]);
        a0[4]  = fmaf(hv0, w1.x,  a0[4]);  a1[4]  = fmaf(hv1, w1.x,  a1[4]);
        a0[5]  = fmaf(hv0, w1.y,  a0[5]);  a1[5]  = fmaf(hv1, w1.y,  a1[5]);
        a0[6]  = fmaf(hv0, w1.z,  a0[6]);  a1[6]  = fmaf(hv1, w1.z,  a1[6]);
        a0[7]  = fmaf(hv0, w1.w,  a0[7]);  a1[7]  = fmaf(hv1, w1.w,  a1[7]);
        a0[8]  = fmaf(hv0, w2.x,  a0[8]);  a1[8]  = fmaf(hv1, w2.x,  a1[8]);
        a0[9]  = fmaf(hv0, w2.y,  a0[9]);  a1[9]  = fmaf(hv1, w2.y,  a1[9]);
        a0[10] = fmaf(hv0, w2.z,  a0[10]); a1[10] = fmaf(hv1, w2.z,  a1[10]);
        a0[11] = fmaf(hv0, w2.w,  a0[11]); a1[11] = fmaf(hv1, w2.w,  a1[11]);
        a0[12] = fmaf(hv0, w3.x,  a0[12]); a1[12] = fmaf(hv1, w3.x,  a1[12]);
        a0[13] = fmaf(hv0, w3.y,  a0[13]); a1[13] = fmaf(hv1, w3.y,  a1[13]);
        a0[14] = fmaf(hv0, w3.z,  a0[14]); a1[14] = fmaf(hv1, w3.z,  a1[14]);
        a0[15] = fmaf(hv0, w3.w,  a0[15]); a1[15] = fmaf(hv1, w3.w,  a1[15]);
        a0[16] = fmaf(hv0, w4v.x, a0[16]); a1[16] = fmaf(hv1, w4v.x, a1[16]);
        a0[17] = fmaf(hv0, w4v.y, a0[17]); a1[17] = fmaf(hv1, w4v.y, a1[17]);
        a0[18] = fmaf(hv0, w4v.z, a0[18]); a1[18] = fmaf(hv1, w4v.z, a1[18]);
        a0[19] = fmaf(hv0, w4v.w, a0[19]); a1[19] = fmaf(hv1, w4v.w, a1[19]);
    }
#pragma unroll
    for (int off = 32; off; off >>= 1) {
#pragma unroll
        for (int a = 0; a < NACT; ++a) {
            a0[a] += __shfl_xor(a0[a], off, 64);
            a1[a] += __shfl_xor(a1[a], off, 64);
        }
    }

    const int c1 = ctr[1], c2 = ctr[2], c3 = ctr[3];
    const int fmt = (c1 > 0) ? 0 : ((c2 > 0 || c3 > 0) ? 2 : 1);

    finish_row(a0, b2, mask, real_actions, fmt, rowBase + lr0,     out, &ctr[4], flagList, lane);
    finish_row(a1, b2, mask, real_actions, fmt, rowBase + lr0 + 1, out, &ctr[4], flagList, lane);
}

// ---------------- refine pass 1: exact f32 hidden rows (TLP version) ----------------
__global__ __launch_bounds__(256) void refine_hidden_kernel(
    const float* __restrict__ A0, const float* __restrict__ A1,
    const float* __restrict__ A2, const float* __restrict__ A3,
    const float* __restrict__ W1, const float* __restrict__ b1,
    const int* __restrict__ ctr, const int* __restrict__ list,
    float* __restrict__ hiddenR, int cap)
{
    __shared__ float xs[2][KTOT];
    __shared__ float red[2][4][64];
    const int tid = threadIdx.x;
    int count = ctr[4]; if (count > cap) count = cap;
    const int total = ((count + 1) >> 1) << 4;

    for (int u = blockIdx.x; u < total; u += gridDim.x) {
        const int p  = u >> 4;
        const int f0 = 2 * p;
        const int f1 = (2 * p + 1 < count) ? (2 * p + 1) : f0;
        const int r0 = list[f0];
        const int r1 = list[f1];
        const int colBase = (u & 15) << 6;

        for (int i = tid; i < KTOT; i += 256) {
            const float* seg = (i < 1024) ? A0 : (i < 2048) ? A1 : (i < 3072) ? A2 : A3;
            xs[0][i] = seg[(size_t)r0 * HD + (i & 1023)];
            xs[1][i] = seg[(size_t)r1 * HD + (i & 1023)];
        }
        __syncthreads();

        const int col   = colBase + (tid & 63);
        const int kbase = (tid >> 6) << 10;
        const float* Wc = W1 + col;
        float acc0 = 0.f, acc1 = 0.f;

        float wa[16], wb[16];
#pragma unroll
        for (int v = 0; v < 16; ++v) wa[v] = Wc[(size_t)(kbase + v) * HD];
#pragma unroll
        for (int v = 0; v < 16; ++v) wb[v] = Wc[(size_t)(kbase + 16 + v) * HD];

        const int kend = kbase + 1024;
        for (int k0 = kbase; k0 < kend; k0 += 32) {
#pragma unroll
            for (int v = 0; v < 16; ++v) {
                acc0 = fmaf(xs[0][k0 + v], wa[v], acc0);
                acc1 = fmaf(xs[1][k0 + v], wa[v], acc1);
            }
            if (k0 + 32 < kend) {
#pragma unroll
                for (int v = 0; v < 16; ++v)
                    wa[v] = Wc[(size_t)(k0 + 32 + v) * HD];
            }
#pragma unroll
            for (int v = 0; v < 16; ++v) {
                acc0 = fmaf(xs[0][k0 + 16 + v], wb[v], acc0);
                acc1 = fmaf(xs[1][k0 + 16 + v], wb[v], acc1);
            }
            if (k0 + 48 < kend) {
#pragma unroll
                for (int v = 0; v < 16; ++v)
                    wb[v] = Wc[(size_t)(k0 + 48 + v) * HD];
            }
        }

        red[0][tid >> 6][tid & 63] = acc0;
        red[1][tid >> 6][tid & 63] = acc1;
        __syncthreads();

        if (tid < 128) {
            const int r = tid >> 6, c = tid & 63;
            const float s = red[r][0][c] + red[r][1][c] + red[r][2][c] + red[r][3][c];
            const int f = r ? f1 : f0;
            hiddenR[(size_t)f * HD + colBase + c] = tanhf(s + b1[colBase + c]);
        }
        __syncthreads();
    }
}

// ---------------- refine pass 2: exact head for flagged rows ----------------
__global__ __launch_bounds__(256) void refine_head_kernel(
    const float* __restrict__ hiddenR, const float* __restrict__ W2,
    const float* __restrict__ b2, const void* __restrict__ mask,
    const int* __restrict__ real_actions, const int* __restrict__ ctr,
    const int* __restrict__ list, float* __restrict__ out, int cap)
{
    const int lane = threadIdx.x & 63;
    const int wv   = threadIdx.x >> 6;
    int count = ctr[4]; if (count > cap) count = cap;
    const int c1 = ctr[1], c2 = ctr[2], c3 = ctr[3];
    const int fmt = (c1 > 0) ? 0 : ((c2 > 0 || c3 > 0) ? 2 : 1);

    for (int f = blockIdx.x * 4 + wv; f < count; f += gridDim.x * 4) {
        const int row = list[f];
        const float* hrow = hiddenR + (size_t)f * HD;
        float a20[NACT];
#pragma unroll
        for (int a = 0; a < NACT; ++a) a20[a] = 0.f;
#pragma unroll 4
        for (int m = 0; m < 16; ++m) {
            const int h = lane + 64 * m;
            const float hv = hrow[h];
            const float4* w4 = (const float4*)(W2 + (size_t)h * NACT);
            const float4 w0 = w4[0], w1 = w4[1], w2 = w4[2], w3 = w4[3], w4v = w4[4];
            a20[0]  = fmaf(hv, w0.x,  a20[0]);  a20[1]  = fmaf(hv, w0.y,  a20[1]);
            a20[2]  = fmaf(hv, w0.z,  a20[2]);  a20[3]  = fmaf(hv, w0.w,  a20[3]);
            a20[4]  = fmaf(hv, w1.x,  a20[4]);  a20[5]  = fmaf(hv, w1.y,  a20[5]);
            a20[6]  = fmaf(hv, w1.z,  a20[6]);  a20[7]  = fmaf(hv, w1.w,  a20[7]);
            a20[8]  = fmaf(hv, w2.x,  a20[8]);  a20[9]  = fmaf(hv, w2.y,  a20[9]);
            a20[10] = fmaf(hv, w2.z,  a20[10]); a20[11] = fmaf(hv, w2.w,  a20[11]);
            a20[12] = fmaf(hv, w3.x,  a20[12]); a20[13] = fmaf(hv, w3.y,  a20[13]);
            a20[14] = fmaf(hv, w3.z,  a20[14]); a20[15] = fmaf(hv, w3.w,  a20[15]);
            a20[16] = fmaf(hv, w4v.x, a20[16]); a20[17] = fmaf(hv, w4v.y, a20[17]);
            a20[18] = fmaf(hv, w4v.z, a20[18]); a20[19] = fmaf(hv, w4v.w, a20[19]);
        }
#pragma unroll
        for (int off = 32; off; off >>= 1) {
#pragma unroll
            for (int a = 0; a < NACT; ++a) a20[a] += __shfl_xor(a20[a], off, 64);
        }
        finish_row(a20, b2, mask, real_actions, fmt, row, out, nullptr, nullptr, lane);
    }
}

// ---------------- launcher ----------------
extern "C" void kernel_launch(void* const* d_in, const int* in_sizes, int n_in,
                              void* d_out, int out_size, void* d_ws, size_t ws_size,
                              hipStream_t stream)
{
    const float* buf_h = (const float*)d_in[0];
    const float* stk_h = (const float*)d_in[1];
    const float* out_h = (const float*)d_in[2];
    const float* act_h = (const float*)d_in[3];
    const float* W1    = (const float*)d_in[4];
    const float* b1    = (const float*)d_in[5];
    const float* W2    = (const float*)d_in[6];
    const float* b2    = (const float*)d_in[7];
    const void*  mask  = d_in[8];
    const int*   ra    = (const int*)d_in[9];
    float*       out   = (float*)d_out;

    // ws layout:
    //   [0,256)          : ctr (mask byte counters 0..3, flag count at [4])
    //   [256, 256+64K)   : flagged-row list (int[16384])
    //   then 16MB        : Wp tile images (8 nt128 x 128 kt x 16KB)
    //   then 64MB        : hidden (f32, 16384 x 1024) -- reused as hiddenR by refine
    int*  ctr      = (int*)d_ws;
    int*  flagList = (int*)((char*)d_ws + 256);
    char* Wp       = (char*)d_ws + 256 + 65536;
    const size_t wpBytes = (size_t)8 * KT_N * 16384;           // 16 MiB
    float* hidden  = (float*)(Wp + wpBytes);

    hipMemsetAsync(d_ws, 0, 256, stream);
    detect_mask_kernel<<<64, 256, 0, stream>>>(
        (const unsigned int*)mask, BTOT * NACT / 4, ctr);
    wpack_kernel<<<8 * KT_N, 256, 0, stream>>>(W1, Wp);

    // 128 KiB dynamic LDS opt-in (deterministic, host-side, capture-safe)
    hipFuncSetAttribute((const void*)gemm1_mfma_kernel,
                        hipFuncAttributeMaxDynamicSharedMemorySize, 131072);

    gemm1_mfma_kernel<<<256, 512, 131072, stream>>>(
        buf_h, stk_h, out_h, act_h, Wp, b1, hidden);
    head_kernel<<<BTOT / 8, 256, 0, stream>>>(
        hidden, W2, b2, mask, ra, ctr, flagList, out, 0);

    // refine: hiddenR aliases hidden (dead after head)
    float* hiddenR = hidden;
    refine_hidden_kernel<<<2048, 256, 0, stream>>>(
        buf_h, stk_h, out_h, act_h, W1, b1, ctr, flagList, hiddenR, BTOT);
    refine_head_kernel<<<64, 256, 0, stream>>>(
        hiddenR, W2, b2, mask, ra, ctr, flagList, out, BTOT);
}